// Round 4
// baseline (1576.785 us; speedup 1.0000x reference)
//
#include <hip/hip_runtime.h>
#include <hip/hip_bf16.h>
#include <math.h>

#define DIMC   256
#define LSP    4096
#define BATCH  8
#define DINNER 512
#define NHEADS 8
#define HEADDIM 64
#define DSTATE 64
#define CONVDIM 640
#define DPROJ  1160
#define CHUNK  256
#define NCHUNK 16

typedef unsigned short u16;

__device__ __forceinline__ float bf2f(u16 u){ return __uint_as_float(((unsigned int)u)<<16); }
__device__ __forceinline__ u16 f2bf(float f){
  unsigned int x = __float_as_uint(f);
  unsigned int r = (x + 0x7fffu + ((x>>16)&1u)) >> 16;
  return (u16)r;
}
__device__ __forceinline__ float softplusf(float x){ return (x > 20.f) ? x : log1pf(expf(x)); }
__device__ __forceinline__ float siluf(float x){ return x / (1.f + expf(-x)); }

// ---------------- LayerNorm over channel dim (fp32 in, bf16 out) ----------------
__global__ void ln_kernel(const float* __restrict__ X, const float* __restrict__ lnw,
                          const float* __restrict__ lnb, u16* __restrict__ XN) {
  int pos = blockIdx.x*256 + threadIdx.x;
  int b = pos >> 12, l = pos & (LSP-1);
  const float* xb = X + ((size_t)b*DIMC)*LSP + l;
  float sum=0.f, sq=0.f;
  for (int c=0;c<DIMC;c++){ float v=xb[(size_t)c*LSP]; sum+=v; sq+=v*v; }
  float mu = sum*(1.f/DIMC);
  float var = sq*(1.f/DIMC) - mu*mu;
  float rs = rsqrtf(var + 1e-5f);
  u16* ob = XN + ((size_t)b*DIMC)*LSP + l;
  for (int c=0;c<DIMC;c++){
    float v=xb[(size_t)c*LSP];
    ob[(size_t)c*LSP] = f2bf((v-mu)*rs*lnw[c] + lnb[c]);
  }
}

// ---------------- GEMM1: ZXBCDT = in_proj_w (fp32 MxK) @ XN (bf16 KxLSP), split outputs ----------------
__global__ void gemm_in_kernel(const float* __restrict__ A, const u16* __restrict__ Bmat,
                               u16* __restrict__ Z, u16* __restrict__ XBC, u16* __restrict__ DT) {
  __shared__ float As[16][65];
  __shared__ float Bs[16][65];
  int tid = threadIdx.x;
  int b = blockIdx.z;
  int m0 = blockIdx.y*64, n0 = blockIdx.x*64;
  const int M = DPROJ, K = DIMC;
  const u16* Bb = Bmat + (size_t)b*K*LSP;
  float acc[4][4];
  #pragma unroll
  for(int i=0;i<4;i++)
    #pragma unroll
    for(int j=0;j<4;j++) acc[i][j]=0.f;
  int lmm = tid>>2, lkq = (tid&3)*4;
  int lkk = tid>>4, lnn = (tid&15)*4;
  int ty4 = (tid>>4)*4, tx4 = (tid&15)*4;
  for (int k0=0;k0<K;k0+=16){
    __syncthreads();
    int row = m0 + lmm;
    float4 av = make_float4(0.f,0.f,0.f,0.f);
    if (row < M) av = *(const float4*)(A + (size_t)row*K + k0 + lkq);
    As[lkq+0][lmm]=av.x; As[lkq+1][lmm]=av.y; As[lkq+2][lmm]=av.z; As[lkq+3][lmm]=av.w;
    ushort4 bv = *(const ushort4*)(Bb + (size_t)(k0+lkk)*LSP + n0 + lnn);
    Bs[lkk][lnn+0]=bf2f(bv.x); Bs[lkk][lnn+1]=bf2f(bv.y);
    Bs[lkk][lnn+2]=bf2f(bv.z); Bs[lkk][lnn+3]=bf2f(bv.w);
    __syncthreads();
    #pragma unroll
    for (int kk=0;kk<16;kk++){
      float a0=As[kk][ty4+0],a1=As[kk][ty4+1],a2=As[kk][ty4+2],a3=As[kk][ty4+3];
      float b0=Bs[kk][tx4+0],b1=Bs[kk][tx4+1],b2=Bs[kk][tx4+2],b3=Bs[kk][tx4+3];
      acc[0][0]+=a0*b0; acc[0][1]+=a0*b1; acc[0][2]+=a0*b2; acc[0][3]+=a0*b3;
      acc[1][0]+=a1*b0; acc[1][1]+=a1*b1; acc[1][2]+=a1*b2; acc[1][3]+=a1*b3;
      acc[2][0]+=a2*b0; acc[2][1]+=a2*b1; acc[2][2]+=a2*b2; acc[2][3]+=a2*b3;
      acc[3][0]+=a3*b0; acc[3][1]+=a3*b1; acc[3][2]+=a3*b2; acc[3][3]+=a3*b3;
    }
  }
  #pragma unroll
  for (int i=0;i<4;i++){
    int row = m0+ty4+i;
    if (row < M){
      u16* orow;
      if (row < DINNER)               orow = Z   + ((size_t)b*DINNER  + row)          *LSP;
      else if (row < DINNER+CONVDIM)  orow = XBC + ((size_t)b*CONVDIM + (row-DINNER)) *LSP;
      else                            orow = DT  + ((size_t)b*NHEADS  + (row-DINNER-CONVDIM))*LSP;
      ushort4 o; o.x=f2bf(acc[i][0]); o.y=f2bf(acc[i][1]); o.z=f2bf(acc[i][2]); o.w=f2bf(acc[i][3]);
      *(ushort4*)(orow + n0 + tx4) = o;
    }
  }
}

// ---------------- GEMM2: out = out_proj_w (fp32 MxK) @ YN (bf16 KxLSP) + x (fp32), fp32 out ----------
__global__ void gemm_out_kernel(const float* __restrict__ A, const u16* __restrict__ Bmat,
                                const float* __restrict__ Res, float* __restrict__ Out) {
  __shared__ float As[16][65];
  __shared__ float Bs[16][65];
  int tid = threadIdx.x;
  int b = blockIdx.z;
  int m0 = blockIdx.y*64, n0 = blockIdx.x*64;
  const int M = DIMC, K = DINNER;
  const u16* Bb = Bmat + (size_t)b*K*LSP;
  float acc[4][4];
  #pragma unroll
  for(int i=0;i<4;i++)
    #pragma unroll
    for(int j=0;j<4;j++) acc[i][j]=0.f;
  int lmm = tid>>2, lkq = (tid&3)*4;
  int lkk = tid>>4, lnn = (tid&15)*4;
  int ty4 = (tid>>4)*4, tx4 = (tid&15)*4;
  for (int k0=0;k0<K;k0+=16){
    __syncthreads();
    int row = m0 + lmm;
    float4 av = *(const float4*)(A + (size_t)row*K + k0 + lkq);
    As[lkq+0][lmm]=av.x; As[lkq+1][lmm]=av.y; As[lkq+2][lmm]=av.z; As[lkq+3][lmm]=av.w;
    ushort4 bv = *(const ushort4*)(Bb + (size_t)(k0+lkk)*LSP + n0 + lnn);
    Bs[lkk][lnn+0]=bf2f(bv.x); Bs[lkk][lnn+1]=bf2f(bv.y);
    Bs[lkk][lnn+2]=bf2f(bv.z); Bs[lkk][lnn+3]=bf2f(bv.w);
    __syncthreads();
    #pragma unroll
    for (int kk=0;kk<16;kk++){
      float a0=As[kk][ty4+0],a1=As[kk][ty4+1],a2=As[kk][ty4+2],a3=As[kk][ty4+3];
      float b0=Bs[kk][tx4+0],b1=Bs[kk][tx4+1],b2=Bs[kk][tx4+2],b3=Bs[kk][tx4+3];
      acc[0][0]+=a0*b0; acc[0][1]+=a0*b1; acc[0][2]+=a0*b2; acc[0][3]+=a0*b3;
      acc[1][0]+=a1*b0; acc[1][1]+=a1*b1; acc[1][2]+=a1*b2; acc[1][3]+=a1*b3;
      acc[2][0]+=a2*b0; acc[2][1]+=a2*b1; acc[2][2]+=a2*b2; acc[2][3]+=a2*b3;
      acc[3][0]+=a3*b0; acc[3][1]+=a3*b1; acc[3][2]+=a3*b2; acc[3][3]+=a3*b3;
    }
  }
  #pragma unroll
  for (int i=0;i<4;i++){
    int row = m0+ty4+i;
    size_t obase = ((size_t)b*M + row)*LSP + n0 + tx4;
    float4 o;
    o.x = acc[i][0]+Res[obase+0]; o.y = acc[i][1]+Res[obase+1];
    o.z = acc[i][2]+Res[obase+2]; o.w = acc[i][3]+Res[obase+3];
    *(float4*)(Out + obase) = o;
  }
}

// ---------------- Depthwise 3x3 conv + bias + SiLU, IN-PLACE on XBC ----------------
__global__ void conv_kernel(u16* __restrict__ XBC, const float* __restrict__ CW,
                            const float* __restrict__ CB){
  int ch = blockIdx.x, b = blockIdx.y, tid = threadIdx.x;
  __shared__ float plane[66*66];
  u16* base = XBC + ((size_t)b*CONVDIM + ch)*LSP;
  for (int idx=tid; idx<66*66; idx+=256){
    int yy = idx/66 - 1, xx = idx%66 - 1;
    float v = 0.f;
    if (yy>=0 && yy<64 && xx>=0 && xx<64) v = bf2f(base[yy*64+xx]);
    plane[idx] = v;
  }
  float wg[9];
  #pragma unroll
  for (int t=0;t<9;t++) wg[t] = CW[ch*9+t];
  float bias = CB[ch];
  __syncthreads();
  for (int r=0;r<16;r++){
    int pix = tid + r*256;
    int y = pix>>6, x = pix&63;
    float s=0.f;
    #pragma unroll
    for(int dy=0;dy<3;dy++)
      #pragma unroll
      for(int dx=0;dx<3;dx++) s += plane[(y+dy)*66 + x+dx]*wg[dy*3+dx];
    base[pix] = f2bf(siluf(s + bias));
  }
}

// ---------------- SSD: per-chunk states: states[n][p] = sum_t B[t][n]*exp(atot-acs[t])*dt[t]*xs[t][p]
__global__ void ssd_states_kernel(const u16* __restrict__ DT, const u16* __restrict__ XBC,
                                  const float* __restrict__ A_log, const float* __restrict__ dt_bias,
                                  float* __restrict__ STATES, float* __restrict__ DASUM){
  int c = blockIdx.x, h = blockIdx.y, b = blockIdx.z, tid = threadIdx.x;
  __shared__ float acs[CHUNK];
  __shared__ float dtb[CHUNK];
  __shared__ float wdec[CHUNK];
  __shared__ float Bt[64][65];
  __shared__ float Xt[64][65];
  float raw = bf2f(DT[((size_t)b*NHEADS + h)*LSP + c*CHUNK + tid]);
  float dtv = softplusf(raw + dt_bias[h]);
  float Ah = -expf(A_log[h]);
  dtb[tid] = dtv;
  acs[tid] = dtv*Ah;
  __syncthreads();
  for (int off=1; off<256; off<<=1){
    float add = (tid>=off)? acs[tid-off] : 0.f;
    __syncthreads();
    acs[tid] += add;
    __syncthreads();
  }
  float atot = acs[CHUNK-1];
  if (tid==0) DASUM[((size_t)b*NHEADS + h)*NCHUNK + c] = atot;
  wdec[tid] = expf(atot - acs[tid]);
  float acc[16];
  #pragma unroll
  for (int i=0;i<16;i++) acc[i]=0.f;
  int n = tid>>2, pp0 = (tid&3)*16;
  int tt = tid&63, nb = tid>>6;
  const size_t lbase = (size_t)c*CHUNK;
  for (int t0=0;t0<CHUNK;t0+=64){
    __syncthreads();
    for (int i=0;i<16;i++){
      int nn = i*4 + nb;
      Bt[tt][nn] = bf2f(XBC[((size_t)b*CONVDIM + DINNER + nn)*LSP + lbase + t0 + tt]);
      float xsv = bf2f(XBC[((size_t)b*CONVDIM + h*HEADDIM + nn)*LSP + lbase + t0 + tt]);
      Xt[tt][nn] = xsv * dtb[t0+tt];
    }
    __syncthreads();
    for (int t2=0;t2<64;t2++){
      float bw = Bt[t2][n]*wdec[t0+t2];
      #pragma unroll
      for (int i=0;i<16;i++) acc[i] += bw*Xt[t2][pp0+i];
    }
  }
  float* dst = STATES + (((size_t)b*NHEADS + h)*NCHUNK + c)*4096 + n*64 + pp0;
  #pragma unroll
  for (int i=0;i<16;i+=4)
    *(float4*)(dst+i) = make_float4(acc[i],acc[i+1],acc[i+2],acc[i+3]);
}

// ---------------- SSD: inter-chunk sequential scan ----------------
__global__ void ssd_scan_kernel(const float* __restrict__ STATES, const float* __restrict__ DASUM,
                                float* __restrict__ PREV){
  int g = blockIdx.x, h = blockIdx.y, b = blockIdx.z, tid = threadIdx.x;
  int e = g*256 + tid;
  size_t hb = (size_t)b*NHEADS + h;
  size_t base = hb*NCHUNK*4096 + e;
  float s = 0.f;
  for (int c=0;c<NCHUNK;c++){
    PREV[base + (size_t)c*4096] = s;
    float dec = expf(DASUM[hb*NCHUNK + c]);
    s = s*dec + STATES[base + (size_t)c*4096];
  }
}

// ---------------- SSD: Y = Y_diag + Y_off + D*xs ----------------
__global__ __launch_bounds__(256,1) void ssd_y_kernel(const u16* __restrict__ DT, const u16* __restrict__ XBC,
                            const float* __restrict__ A_log, const float* __restrict__ dt_bias,
                            const float* __restrict__ Dp, const float* __restrict__ PREV,
                            u16* __restrict__ YG){
  int c = blockIdx.x, h = blockIdx.y, b = blockIdx.z, tid = threadIdx.x;
  __shared__ float acs[CHUNK];
  __shared__ float dtb[CHUNK];
  __shared__ float prevs[64][64];
  __shared__ float Bs[64][65];
  __shared__ float Xs[64][65];
  float raw = bf2f(DT[((size_t)b*NHEADS + h)*LSP + c*CHUNK + tid]);
  float dtv = softplusf(raw + dt_bias[h]);
  float Ah = -expf(A_log[h]);
  dtb[tid] = dtv;
  acs[tid] = dtv*Ah;
  __syncthreads();
  for (int off=1; off<256; off<<=1){
    float add = (tid>=off)? acs[tid-off] : 0.f;
    __syncthreads();
    acs[tid] += add;
    __syncthreads();
  }
  {
    const float* psrc = PREV + (((size_t)b*NHEADS+h)*NCHUNK + c)*4096;
    for (int idx=tid; idx<4096; idx+=256) ((float*)prevs)[idx] = psrc[idx];
  }
  float creg[64];
  const size_t lb = (size_t)c*CHUNK + tid;
  #pragma unroll
  for (int n=0;n<64;n++)
    creg[n] = bf2f(XBC[((size_t)b*CONVDIM + DINNER + DSTATE + n)*LSP + lb]);
  __syncthreads();
  float accv[64];
  #pragma unroll
  for (int p=0;p<64;p++) accv[p]=0.f;
  for (int n=0;n<64;n++){
    float cv = creg[n];
    #pragma unroll
    for (int p=0;p<64;p++) accv[p] += cv*prevs[n][p];
  }
  float eA = expf(acs[tid]);
  #pragma unroll
  for (int p=0;p<64;p++) accv[p] *= eA;
  int wv = tid>>6;
  int tt = tid&63, nb = tid>>6;
  for (int st=0; st<4; st++){
    __syncthreads();
    for (int i=0;i<16;i++){
      int nn = i*4+nb;
      Bs[tt][nn] = bf2f(XBC[((size_t)b*CONVDIM + DINNER + nn)*LSP + (size_t)c*CHUNK + st*64 + tt]);
      float xsv = bf2f(XBC[((size_t)b*CONVDIM + h*HEADDIM + nn)*LSP + (size_t)c*CHUNK + st*64 + tt]);
      Xs[tt][nn] = xsv*dtb[st*64+tt];
    }
    __syncthreads();
    if (st > wv) continue;
    bool full = (st < wv);
    for (int ss=0; ss<64; ss++){
      int s = st*64+ss;
      float dot = 0.f;
      #pragma unroll
      for (int n=0;n<64;n++) dot += creg[n]*Bs[ss][n];
      if (full || s <= tid){
        float sc = expf(acs[tid]-acs[s])*dot;
        #pragma unroll
        for (int p=0;p<64;p++) accv[p] += sc*Xs[ss][p];
      }
    }
  }
  float Dh = Dp[h];
  u16* dst = YG + ((size_t)b*DINNER + h*HEADDIM)*LSP + (size_t)c*CHUNK + tid;
  for (int p=0;p<64;p++){
    float xsv = bf2f(XBC[((size_t)b*CONVDIM + h*HEADDIM + p)*LSP + (size_t)c*CHUNK + tid]);
    dst[(size_t)p*LSP] = f2bf(accv[p] + Dh*xsv);
  }
}

// ---------------- gate (silu(z)) + RMSNorm, IN-PLACE on YG ----------------
__global__ void gate_kernel(u16* __restrict__ YG, const u16* __restrict__ Z,
                            const float* __restrict__ rmsw){
  int pos = blockIdx.x*256 + threadIdx.x;
  int b = pos>>12, l = pos&(LSP-1);
  u16* yb = YG + (size_t)b*DINNER*LSP + l;
  const u16* zb = Z + (size_t)b*DINNER*LSP + l;
  float sq=0.f;
  for (int d=0;d<DINNER;d++){
    float y = bf2f(yb[(size_t)d*LSP]);
    float zv = bf2f(zb[(size_t)d*LSP]);
    float g = y * siluf(zv);
    sq += g*g;
  }
  float rinv = rsqrtf(sq*(1.f/DINNER) + 1e-5f);
  for (int d=0;d<DINNER;d++){
    float y = bf2f(yb[(size_t)d*LSP]);
    float zv = bf2f(zb[(size_t)d*LSP]);
    float g = y * siluf(zv);
    yb[(size_t)d*LSP] = f2bf(g*rinv*rmsw[d]);
  }
}

extern "C" void kernel_launch(void* const* d_in, const int* in_sizes, int n_in,
                              void* d_out, int out_size, void* d_ws, size_t ws_size,
                              hipStream_t stream) {
  const float* x     = (const float*)d_in[0];
  const float* lnw   = (const float*)d_in[1];
  const float* lnb   = (const float*)d_in[2];
  const float* inpw  = (const float*)d_in[3];
  const float* convw = (const float*)d_in[4];
  const float* convb = (const float*)d_in[5];
  const float* alog  = (const float*)d_in[6];
  const float* Dp    = (const float*)d_in[7];
  const float* dtbi  = (const float*)d_in[8];
  const float* rmsw  = (const float*)d_in[9];
  const float* outw  = (const float*)d_in[10];
  float* out = (float*)d_out;

  char* ws = (char*)d_ws;
  size_t off = 0;
  auto alloc = [&](size_t bytes)->void*{ void* p = ws+off; off += (bytes+255)&~(size_t)255; return p; };
  // region A: XN (bf16, 16.78MB) then STATES (fp32, 16.78MB) — XN dead after gemm1
  char*  RA     = (char*) alloc((size_t)BATCH*NHEADS*NCHUNK*4096*4);
  u16*   XN     = (u16*)RA;
  float* STATES = (float*)RA;
  float* PREV   = (float*)alloc((size_t)BATCH*NHEADS*NCHUNK*4096*4);   // 16.78MB
  u16*   Z      = (u16*)  alloc((size_t)BATCH*DINNER*LSP*2);           // 33.55MB
  u16*   XBC    = (u16*)  alloc((size_t)BATCH*CONVDIM*LSP*2);          // 41.94MB
  u16*   DTb    = (u16*)  alloc((size_t)BATCH*NHEADS*LSP*2);           // 0.52MB
  float* DASUM  = (float*)alloc((size_t)BATCH*NHEADS*NCHUNK*4);
  u16*   YG     = (u16*)  alloc((size_t)BATCH*DINNER*LSP*2);           // 33.55MB
  // total ~143.9MB

  ln_kernel<<<dim3(BATCH*LSP/256),256,0,stream>>>(x,lnw,lnb,XN);
  gemm_in_kernel<<<dim3(LSP/64,(DPROJ+63)/64,BATCH),256,0,stream>>>(inpw, XN, Z, XBC, DTb);
  conv_kernel<<<dim3(CONVDIM,BATCH),256,0,stream>>>(XBC, convw, convb);
  ssd_states_kernel<<<dim3(NCHUNK,NHEADS,BATCH),256,0,stream>>>(DTb,XBC,alog,dtbi,STATES,DASUM);
  ssd_scan_kernel<<<dim3(16,NHEADS,BATCH),256,0,stream>>>(STATES,DASUM,PREV);
  ssd_y_kernel<<<dim3(NCHUNK,NHEADS,BATCH),256,0,stream>>>(DTb,XBC,alog,dtbi,Dp,PREV,YG);
  gate_kernel<<<dim3(BATCH*LSP/256),256,0,stream>>>(YG,Z,rmsw);
  gemm_out_kernel<<<dim3(LSP/64,DIMC/64,BATCH),256,0,stream>>>(outw, YG, x, out);
}

// Round 5
// 638.680 us; speedup vs baseline: 2.4688x; 2.4688x over previous
//
#include <hip/hip_runtime.h>
#include <hip/hip_bf16.h>
#include <math.h>

#define DIMC   256
#define LSP    4096
#define BATCH  8
#define DINNER 512
#define NHEADS 8
#define HEADDIM 64
#define DSTATE 64
#define CONVDIM 640
#define DPROJ  1160
#define MPAD   1280
#define CHUNK  256
#define NCHUNK 16

typedef unsigned short u16;
typedef __attribute__((ext_vector_type(8))) unsigned short u16x8;
typedef __attribute__((ext_vector_type(8))) short s16x8;
typedef __attribute__((ext_vector_type(4))) float f32x4;

#define MFMA16(a,b,c) __builtin_amdgcn_mfma_f32_16x16x32_bf16((s16x8)(a),(s16x8)(b),(c),0,0,0)

__device__ __forceinline__ float bf2f(u16 u){ return __uint_as_float(((unsigned int)u)<<16); }
__device__ __forceinline__ u16 f2bf(float f){
  unsigned int x = __float_as_uint(f);
  unsigned int r = (x + 0x7fffu + ((x>>16)&1u)) >> 16;
  return (u16)r;
}
__device__ __forceinline__ float softplusf(float x){ return (x > 20.f) ? x : log1pf(expf(x)); }
__device__ __forceinline__ float siluf(float x){ return x / (1.f + expf(-x)); }
__device__ __forceinline__ u16x8 fscale(u16x8 v, float s){
  u16x8 r;
  #pragma unroll
  for(int j=0;j<8;j++) r[j] = f2bf(bf2f(v[j])*s);
  return r;
}

// ---------------- weight fp32 -> bf16 (with trailing-row zero pad) ----------------
__global__ void convert_w(const float* __restrict__ src, u16* __restrict__ dst,
                          int total, int valid){
  int i = blockIdx.x*256 + threadIdx.x;
  if (i >= total) return;
  dst[i] = (i < valid) ? f2bf(src[i]) : (u16)0;
}

// ---------------- LayerNorm: x [b][c][l] fp32 -> XNT [b][l][c] bf16 ----------------
__global__ void ln_kernel(const float* __restrict__ X, const float* __restrict__ lnw,
                          const float* __restrict__ lnb, u16* __restrict__ XNT) {
  int pos = blockIdx.x*256 + threadIdx.x;
  int b = pos >> 12, l = pos & (LSP-1);
  const float* xb = X + ((size_t)b*DIMC)*LSP + l;
  float sum=0.f, sq=0.f;
  for (int c=0;c<DIMC;c++){ float v=xb[(size_t)c*LSP]; sum+=v; sq+=v*v; }
  float mu = sum*(1.f/DIMC);
  float var = sq*(1.f/DIMC) - mu*mu;
  float rs = rsqrtf(var + 1e-5f);
  u16* ob = XNT + ((size_t)(b*LSP + l))*DIMC;
  for (int c=0;c<DIMC;c++){
    float v=xb[(size_t)c*LSP];
    ob[c] = f2bf((v-mu)*rs*lnw[c] + lnb[c]);
  }
}

// ---------------- GEMM1 (MFMA): [MPADx256 bf16] x [XNT b,l,c] -> Z/XBC/DT planar ----
__global__ void gemm_in_mfma(const u16* __restrict__ A, const u16* __restrict__ Bm,
                             u16* __restrict__ Z, u16* __restrict__ XBC, u16* __restrict__ DT){
  __shared__ u16 As[128][32];
  __shared__ u16 Bs[128][32];
  int tid=threadIdx.x, w=tid>>6, lane=tid&63, l15=lane&15, quad=lane>>4;
  int b=blockIdx.z, m0=blockIdx.y*128, n0=blockIdx.x*128;
  const u16* Bb = Bm + ((size_t)b*LSP + n0)*DIMC;
  f32x4 acc[4][4];
  #pragma unroll
  for(int i=0;i<4;i++)
    #pragma unroll
    for(int j=0;j<4;j++) acc[i][j] = (f32x4){0.f,0.f,0.f,0.f};
  for (int k0=0;k0<DIMC;k0+=32){
    __syncthreads();
    {
      int ch = tid*2;
      int r = ch>>2, o=(ch&3)*8;
      *(u16x8*)&As[r][o] = *(const u16x8*)&A[(size_t)(m0+r)*DIMC + k0 + o];
      *(u16x8*)&Bs[r][o] = *(const u16x8*)&Bb[(size_t)r*DIMC + k0 + o];
      ch++; r = ch>>2; o=(ch&3)*8;
      *(u16x8*)&As[r][o] = *(const u16x8*)&A[(size_t)(m0+r)*DIMC + k0 + o];
      *(u16x8*)&Bs[r][o] = *(const u16x8*)&Bb[(size_t)r*DIMC + k0 + o];
    }
    __syncthreads();
    int mrow = (w>>1)*64, ncol=(w&1)*64;
    u16x8 af[4], bfr[4];
    #pragma unroll
    for(int mt=0;mt<4;mt++) af[mt] = *(const u16x8*)&As[mrow+mt*16+l15][quad*8];
    #pragma unroll
    for(int nt=0;nt<4;nt++) bfr[nt] = *(const u16x8*)&Bs[ncol+nt*16+l15][quad*8];
    #pragma unroll
    for(int mt=0;mt<4;mt++)
      #pragma unroll
      for(int nt=0;nt<4;nt++)
        acc[mt][nt]=MFMA16(af[mt],bfr[nt],acc[mt][nt]);
  }
  #pragma unroll
  for(int mt=0;mt<4;mt++)
    #pragma unroll
    for(int nt=0;nt<4;nt++)
      #pragma unroll
      for(int r=0;r<4;r++){
        int row = m0 + (w>>1)*64 + mt*16 + quad*4 + r;
        if (row>=DPROJ) continue;
        int col = n0 + (w&1)*64 + nt*16 + l15;
        u16 v = f2bf(acc[mt][nt][r]);
        if (row<DINNER)                Z[((size_t)b*DINNER+row)*LSP+col]=v;
        else if (row<DINNER+CONVDIM)   XBC[((size_t)b*CONVDIM+(row-DINNER))*LSP+col]=v;
        else                           DT[((size_t)b*NHEADS+(row-DINNER-CONVDIM))*LSP+col]=v;
      }
}

// ---------------- GEMM2 (MFMA): W2 [256x512 bf16] x YG [b,l,512] + x -> out fp32 ----
__global__ void gemm_out_mfma(const u16* __restrict__ A, const u16* __restrict__ Bm,
                              const float* __restrict__ Res, float* __restrict__ Out){
  __shared__ u16 As[128][32];
  __shared__ u16 Bs[128][32];
  int tid=threadIdx.x, w=tid>>6, lane=tid&63, l15=lane&15, quad=lane>>4;
  int b=blockIdx.z, m0=blockIdx.y*128, n0=blockIdx.x*128;
  const u16* Bb = Bm + ((size_t)b*LSP + n0)*DINNER;
  f32x4 acc[4][4];
  #pragma unroll
  for(int i=0;i<4;i++)
    #pragma unroll
    for(int j=0;j<4;j++) acc[i][j] = (f32x4){0.f,0.f,0.f,0.f};
  for (int k0=0;k0<DINNER;k0+=32){
    __syncthreads();
    {
      int ch = tid*2;
      int r = ch>>2, o=(ch&3)*8;
      *(u16x8*)&As[r][o] = *(const u16x8*)&A[(size_t)(m0+r)*DINNER + k0 + o];
      *(u16x8*)&Bs[r][o] = *(const u16x8*)&Bb[(size_t)r*DINNER + k0 + o];
      ch++; r = ch>>2; o=(ch&3)*8;
      *(u16x8*)&As[r][o] = *(const u16x8*)&A[(size_t)(m0+r)*DINNER + k0 + o];
      *(u16x8*)&Bs[r][o] = *(const u16x8*)&Bb[(size_t)r*DINNER + k0 + o];
    }
    __syncthreads();
    int mrow = (w>>1)*64, ncol=(w&1)*64;
    u16x8 af[4], bfr[4];
    #pragma unroll
    for(int mt=0;mt<4;mt++) af[mt] = *(const u16x8*)&As[mrow+mt*16+l15][quad*8];
    #pragma unroll
    for(int nt=0;nt<4;nt++) bfr[nt] = *(const u16x8*)&Bs[ncol+nt*16+l15][quad*8];
    #pragma unroll
    for(int mt=0;mt<4;mt++)
      #pragma unroll
      for(int nt=0;nt<4;nt++)
        acc[mt][nt]=MFMA16(af[mt],bfr[nt],acc[mt][nt]);
  }
  #pragma unroll
  for(int mt=0;mt<4;mt++)
    #pragma unroll
    for(int nt=0;nt<4;nt++)
      #pragma unroll
      for(int r=0;r<4;r++){
        int row = m0 + (w>>1)*64 + mt*16 + quad*4 + r;
        int col = n0 + (w&1)*64 + nt*16 + l15;
        size_t oi = ((size_t)b*DIMC+row)*LSP+col;
        Out[oi] = acc[mt][nt][r] + Res[oi];
      }
}

// ---------------- Depthwise 3x3 conv + bias + SiLU, IN-PLACE on XBC ----------------
__global__ void conv_kernel(u16* __restrict__ XBC, const float* __restrict__ CW,
                            const float* __restrict__ CB){
  int ch = blockIdx.x, b = blockIdx.y, tid = threadIdx.x;
  __shared__ float plane[66*66];
  u16* base = XBC + ((size_t)b*CONVDIM + ch)*LSP;
  for (int idx=tid; idx<66*66; idx+=256){
    int yy = idx/66 - 1, xx = idx%66 - 1;
    float v = 0.f;
    if (yy>=0 && yy<64 && xx>=0 && xx<64) v = bf2f(base[yy*64+xx]);
    plane[idx] = v;
  }
  float wg[9];
  #pragma unroll
  for (int t=0;t<9;t++) wg[t] = CW[ch*9+t];
  float bias = CB[ch];
  __syncthreads();
  for (int r=0;r<16;r++){
    int pix = tid + r*256;
    int y = pix>>6, x = pix&63;
    float s=0.f;
    #pragma unroll
    for(int dy=0;dy<3;dy++)
      #pragma unroll
      for(int dx=0;dx<3;dx++) s += plane[(y+dy)*66 + x+dx]*wg[dy*3+dx];
    base[pix] = f2bf(siluf(s + bias));
  }
}

// ---------------- SSD states (MFMA): states_T[p][n] = sum_t Xdtw[t][p]*B[t][n] ------
__global__ __launch_bounds__(256,2) void ssd_states_mfma(
    const u16* __restrict__ DT, const u16* __restrict__ XBC,
    const float* __restrict__ A_log, const float* __restrict__ dt_bias,
    float* __restrict__ STATES, float* __restrict__ DASUM){
  int c=blockIdx.x, h=blockIdx.y, b=blockIdx.z;
  int tid=threadIdx.x, w=tid>>6, lane=tid&63, l15=lane&15, quad=lane>>4;
  __shared__ float acs[CHUNK];
  __shared__ float wdt[CHUNK];
  __shared__ u16 Xw[64][136];
  __shared__ u16 Bn[64][136];
  float raw = bf2f(DT[((size_t)b*NHEADS+h)*LSP + c*CHUNK + tid]);
  float dtv = softplusf(raw + dt_bias[h]);
  float Ah = -expf(A_log[h]);
  acs[tid]=dtv*Ah;
  __syncthreads();
  for(int o=1;o<256;o<<=1){
    float add=(tid>=o)?acs[tid-o]:0.f;
    __syncthreads(); acs[tid]+=add; __syncthreads();
  }
  float atot = acs[CHUNK-1];
  if(tid==0) DASUM[((size_t)b*NHEADS+h)*NCHUNK+c]=atot;
  wdt[tid] = dtv*expf(atot-acs[tid]);
  __syncthreads();
  f32x4 acc[4];
  #pragma unroll
  for(int i=0;i<4;i++) acc[i] = (f32x4){0.f,0.f,0.f,0.f};
  size_t cb = (size_t)c*CHUNK;
  for(int th=0; th<2; th++){
    __syncthreads();
    {
      int n=tid&63, q4=tid>>6;
      const u16* Xg = XBC + ((size_t)b*CONVDIM + h*HEADDIM + n)*LSP + cb + th*128;
      const u16* Bg = XBC + ((size_t)b*CONVDIM + DINNER + n)*LSP + cb + th*128;
      #pragma unroll
      for(int i=0;i<4;i++){
        int o = q4*32+i*8;
        u16x8 v = *(const u16x8*)&Xg[o];
        u16x8 wv;
        #pragma unroll
        for(int j=0;j<8;j++) wv[j]=f2bf(bf2f(v[j])*wdt[th*128+o+j]);
        *(u16x8*)&Xw[n][o]=wv;
        *(u16x8*)&Bn[n][o] = *(const u16x8*)&Bg[o];
      }
    }
    __syncthreads();
    #pragma unroll
    for(int k8=0;k8<4;k8++){
      u16x8 a = *(const u16x8*)&Xw[w*16+l15][k8*32+quad*8];
      #pragma unroll
      for(int nt=0;nt<4;nt++){
        u16x8 bb = *(const u16x8*)&Bn[nt*16+l15][k8*32+quad*8];
        acc[nt]=MFMA16(a,bb,acc[nt]);
      }
    }
  }
  float* dst = STATES + (((size_t)b*NHEADS+h)*NCHUNK+c)*4096;
  #pragma unroll
  for(int nt=0;nt<4;nt++)
    #pragma unroll
    for(int r=0;r<4;r++)
      dst[(w*16+quad*4+r)*64 + nt*16+l15] = acc[nt][r];
}

// ---------------- inter-chunk scan -> PREVB bf16 [p][n] per (b,h,c) ----------------
__global__ void ssd_scan_kernel(const float* __restrict__ STATES, const float* __restrict__ DASUM,
                                u16* __restrict__ PREVB){
  int g = blockIdx.x, h = blockIdx.y, b = blockIdx.z, tid = threadIdx.x;
  int e = g*256 + tid;
  size_t hb = (size_t)b*NHEADS + h;
  size_t base = hb*NCHUNK*4096 + e;
  float s = 0.f;
  for (int cc=0;cc<NCHUNK;cc++){
    PREVB[base + (size_t)cc*4096] = f2bf(s);
    s = s*expf(DASUM[hb*NCHUNK + cc]) + STATES[base + (size_t)cc*4096];
  }
}

// ---------------- SSD Y (MFMA, flash-style): one 64-t band per block ----------------
__global__ __launch_bounds__(256,2) void ssd_y_mfma(
    const u16* __restrict__ DT, const u16* __restrict__ XBC,
    const float* __restrict__ A_log, const float* __restrict__ dt_bias,
    const float* __restrict__ Dp, const u16* __restrict__ PREVB,
    u16* __restrict__ YG){
  int bx = blockIdx.x; int c = bx>>2, tb = bx&3;
  int h = blockIdx.y, b = blockIdx.z;
  int tid=threadIdx.x, w=tid>>6, lane=tid&63, l15=lane&15, quad=lane>>4;
  __shared__ float acs[CHUNK];
  __shared__ float dtb[CHUNK];
  __shared__ u16 Ct[64][72];
  __shared__ u16 Xt[64][264];
  __shared__ u16 Bsb[64][72];
  __shared__ u16 P[4][16][72];
  float raw = bf2f(DT[((size_t)b*NHEADS+h)*LSP + c*CHUNK + tid]);
  float dtv = softplusf(raw + dt_bias[h]);
  float Ah = -expf(A_log[h]);
  dtb[tid]=dtv; acs[tid]=dtv*Ah;
  __syncthreads();
  for(int o=1;o<256;o<<=1){
    float add=(tid>=o)?acs[tid-o]:0.f;
    __syncthreads(); acs[tid]+=add; __syncthreads();
  }
  // stage C band [64t][64n] (transpose) and Xdt [64p][s<= (tb+1)*64]
  {
    int n = tid&63, q4 = tid>>6;
    const u16* Cg = XBC + ((size_t)b*CONVDIM + DINNER + DSTATE + n)*LSP + (size_t)c*CHUNK + tb*64;
    #pragma unroll
    for(int i=0;i<2;i++){
      u16x8 v = *(const u16x8*)&Cg[q4*16+i*8];
      #pragma unroll
      for(int j=0;j<8;j++) Ct[q4*16+i*8+j][n]=v[j];
    }
    const u16* Xg = XBC + ((size_t)b*CONVDIM + h*HEADDIM + n)*LSP + (size_t)c*CHUNK;
    int smax = (tb+1)*64;
    int s0 = q4*64;
    if (s0 < smax){
      #pragma unroll
      for(int i=0;i<8;i++){
        u16x8 v = *(const u16x8*)&Xg[s0+i*8];
        u16x8 wv;
        #pragma unroll
        for(int j=0;j<8;j++) wv[j] = f2bf(bf2f(v[j])*dtb[s0+i*8+j]);
        *(u16x8*)&Xt[n][s0+i*8] = wv;
      }
    }
  }
  __syncthreads();
  f32x4 Y[4];
  #pragma unroll
  for(int i=0;i<4;i++) Y[i]=(f32x4){0.f,0.f,0.f,0.f};
  int trow = w*16 + l15;                 // band-local A-frag row
  u16x8 ca0 = *(const u16x8*)&Ct[trow][quad*8];
  u16x8 ca1 = *(const u16x8*)&Ct[trow][32+quad*8];
  // Y_off = (exp(acs[t]) * C) . prev
  {
    float ea = expf(acs[tb*64 + trow]);
    u16x8 a0 = fscale(ca0, ea);
    u16x8 a1 = fscale(ca1, ea);
    const u16* Pg = PREVB + (((size_t)b*NHEADS+h)*NCHUNK + c)*4096;
    #pragma unroll
    for(int pt=0;pt<4;pt++){
      u16x8 b0 = *(const u16x8*)&Pg[(pt*16+l15)*64 + quad*8];
      u16x8 b1 = *(const u16x8*)&Pg[(pt*16+l15)*64 + 32 + quad*8];
      Y[pt]=MFMA16(a0,b0,Y[pt]);
      Y[pt]=MFMA16(a1,b1,Y[pt]);
    }
  }
  // diagonal + causal blocks
  for(int sb=0; sb<=tb; sb++){
    __syncthreads();
    {
      int n=tid&63, q4=tid>>6;
      const u16* Bg = XBC + ((size_t)b*CONVDIM + DINNER + n)*LSP + (size_t)c*CHUNK + sb*64;
      #pragma unroll
      for(int i=0;i<2;i++){
        u16x8 v = *(const u16x8*)&Bg[q4*16+i*8];
        #pragma unroll
        for(int j=0;j<8;j++) Bsb[q4*16+i*8+j][n]=v[j];
      }
    }
    __syncthreads();
    f32x4 S[4];
    #pragma unroll
    for(int st=0;st<4;st++) S[st]=(f32x4){0.f,0.f,0.f,0.f};
    #pragma unroll
    for(int st=0;st<4;st++){
      u16x8 b0 = *(const u16x8*)&Bsb[st*16+l15][quad*8];
      u16x8 b1 = *(const u16x8*)&Bsb[st*16+l15][32+quad*8];
      S[st]=MFMA16(ca0,b0,S[st]);
      S[st]=MFMA16(ca1,b1,S[st]);
    }
    int tloc = tb*64 + w*16 + quad*4;
    #pragma unroll
    for(int st=0;st<4;st++){
      int s = sb*64 + st*16 + l15;
      float as = acs[s];
      #pragma unroll
      for(int r=0;r<4;r++){
        int t = tloc + r;
        float arg = acs[t]-as;
        float e = (s<=t)? expf(arg) : 0.f;
        P[w][quad*4+r][st*16+l15] = f2bf(S[st][r]*e);
      }
    }
    u16x8 p0 = *(const u16x8*)&P[w][l15][quad*8];
    u16x8 p1 = *(const u16x8*)&P[w][l15][32+quad*8];
    #pragma unroll
    for(int pt=0;pt<4;pt++){
      u16x8 x0 = *(const u16x8*)&Xt[pt*16+l15][sb*64+quad*8];
      u16x8 x1 = *(const u16x8*)&Xt[pt*16+l15][sb*64+32+quad*8];
      Y[pt]=MFMA16(p0,x0,Y[pt]);
      Y[pt]=MFMA16(p1,x1,Y[pt]);
    }
  }
  // epilogue: + D*xs, write YG [l][d]
  float Dh = Dp[h];
  size_t lbase = (size_t)b*LSP + c*CHUNK + tb*64;
  #pragma unroll
  for(int pt=0;pt<4;pt++){
    #pragma unroll
    for(int r=0;r<4;r++){
      int tl = w*16 + quad*4 + r;
      int p = pt*16 + l15;
      float xdt = bf2f(Xt[p][tb*64 + tl]);
      float xs = xdt / dtb[tb*64 + tl];
      float y = Y[pt][r] + Dh*xs;
      YG[(lbase + tl)*DINNER + h*HEADDIM + p] = f2bf(y);
    }
  }
}

// ---------------- gate (silu(z)) + RMSNorm, IN-PLACE on YG [l][d] ----------------
__global__ void gate_kernel(u16* __restrict__ YG, const u16* __restrict__ Z,
                            const float* __restrict__ rmsw){
  int pos = blockIdx.x*256 + threadIdx.x;
  int b = pos>>12, l = pos&(LSP-1);
  u16* yb = YG + ((size_t)(b*LSP + l))*DINNER;
  const u16* zb = Z + (size_t)b*DINNER*LSP + l;
  float sq=0.f;
  for (int d=0;d<DINNER;d++){
    float y = bf2f(yb[d]);
    float zv = bf2f(zb[(size_t)d*LSP]);
    float g = y * siluf(zv);
    sq += g*g;
  }
  float rinv = rsqrtf(sq*(1.f/DINNER) + 1e-5f);
  for (int d=0;d<DINNER;d++){
    float y = bf2f(yb[d]);
    float zv = bf2f(zb[(size_t)d*LSP]);
    float g = y * siluf(zv);
    yb[d] = f2bf(g*rinv*rmsw[d]);
  }
}

extern "C" void kernel_launch(void* const* d_in, const int* in_sizes, int n_in,
                              void* d_out, int out_size, void* d_ws, size_t ws_size,
                              hipStream_t stream) {
  const float* x     = (const float*)d_in[0];
  const float* lnw   = (const float*)d_in[1];
  const float* lnb   = (const float*)d_in[2];
  const float* inpw  = (const float*)d_in[3];
  const float* convw = (const float*)d_in[4];
  const float* convb = (const float*)d_in[5];
  const float* alog  = (const float*)d_in[6];
  const float* Dp    = (const float*)d_in[7];
  const float* dtbi  = (const float*)d_in[8];
  const float* rmsw  = (const float*)d_in[9];
  const float* outw  = (const float*)d_in[10];
  float* out = (float*)d_out;

  char* ws = (char*)d_ws;
  size_t off = 0;
  auto alloc = [&](size_t bytes)->void*{ void* p = ws+off; off += (bytes+255)&~(size_t)255; return p; };
  u16*   WPIN   = (u16*)  alloc((size_t)MPAD*DIMC*2);                    // 0.66MB
  u16*   WPOUT  = (u16*)  alloc((size_t)DIMC*DINNER*2);                  // 0.26MB
  // overlay: XNT (bf16 [b][l][c], 16.78MB) dead after gemm_in; STATES fp32 16.78MB after
  char*  RA     = (char*) alloc((size_t)BATCH*NHEADS*NCHUNK*4096*4);
  u16*   XNT    = (u16*)RA;
  float* STATES = (float*)RA;
  u16*   Z      = (u16*)  alloc((size_t)BATCH*DINNER*LSP*2);             // 33.55MB
  u16*   XBC    = (u16*)  alloc((size_t)BATCH*CONVDIM*LSP*2);            // 41.94MB
  u16*   DTb    = (u16*)  alloc((size_t)BATCH*NHEADS*LSP*2);             // 0.52MB
  u16*   PREVB  = (u16*)  alloc((size_t)BATCH*NHEADS*NCHUNK*4096*2);     // 8.39MB
  float* DASUM  = (float*)alloc((size_t)BATCH*NHEADS*NCHUNK*4);
  u16*   YG     = (u16*)  alloc((size_t)BATCH*LSP*DINNER*2);             // 33.55MB

  convert_w<<<(MPAD*DIMC+255)/256,256,0,stream>>>(inpw, WPIN, MPAD*DIMC, DPROJ*DIMC);
  convert_w<<<(DIMC*DINNER+255)/256,256,0,stream>>>(outw, WPOUT, DIMC*DINNER, DIMC*DINNER);
  ln_kernel<<<dim3(BATCH*LSP/256),256,0,stream>>>(x,lnw,lnb,XNT);
  gemm_in_mfma<<<dim3(LSP/128,MPAD/128,BATCH),256,0,stream>>>(WPIN, XNT, Z, XBC, DTb);
  conv_kernel<<<dim3(CONVDIM,BATCH),256,0,stream>>>(XBC, convw, convb);
  ssd_states_mfma<<<dim3(NCHUNK,NHEADS,BATCH),256,0,stream>>>(DTb,XBC,alog,dtbi,STATES,DASUM);
  ssd_scan_kernel<<<dim3(16,NHEADS,BATCH),256,0,stream>>>(STATES,DASUM,PREVB);
  ssd_y_mfma<<<dim3(NCHUNK*4,NHEADS,BATCH),256,0,stream>>>(DTb,XBC,alog,dtbi,Dp,PREVB,YG);
  gate_kernel<<<dim3(BATCH*LSP/256),256,0,stream>>>(YG,Z,rmsw);
  gemm_out_mfma<<<dim3(LSP/128,DIMC/128,BATCH),256,0,stream>>>(WPOUT, YG, x, out);
}

// Round 6
// 440.729 us; speedup vs baseline: 3.5777x; 1.4491x over previous
//
#include <hip/hip_runtime.h>
#include <hip/hip_bf16.h>
#include <math.h>

#define DIMC   256
#define LSP    4096
#define BATCH  8
#define DINNER 512
#define NHEADS 8
#define HEADDIM 64
#define DSTATE 64
#define CONVDIM 640
#define DPROJ  1160
#define MPAD   1280
#define CHUNK  256
#define NCHUNK 16

typedef unsigned short u16;
typedef __attribute__((ext_vector_type(8))) unsigned short u16x8;
typedef __attribute__((ext_vector_type(8))) short s16x8;
typedef __attribute__((ext_vector_type(4))) float f32x4;

#define MFMA16(a,b,c) __builtin_amdgcn_mfma_f32_16x16x32_bf16((s16x8)(a),(s16x8)(b),(c),0,0,0)

__device__ __forceinline__ float bf2f(u16 u){ return __uint_as_float(((unsigned int)u)<<16); }
__device__ __forceinline__ u16 f2bf(float f){
  unsigned int x = __float_as_uint(f);
  unsigned int r = (x + 0x7fffu + ((x>>16)&1u)) >> 16;
  return (u16)r;
}
__device__ __forceinline__ float softplusf(float x){ return (x > 20.f) ? x : log1pf(expf(x)); }
__device__ __forceinline__ float siluf(float x){ return x / (1.f + expf(-x)); }
__device__ __forceinline__ u16x8 fscale(u16x8 v, float s){
  u16x8 r;
  #pragma unroll
  for(int j=0;j<8;j++) r[j] = f2bf(bf2f(v[j])*s);
  return r;
}

// ---------------- weight fp32 -> bf16 (with trailing-row zero pad) ----------------
__global__ void convert_w(const float* __restrict__ src, u16* __restrict__ dst,
                          int total, int valid){
  int i = blockIdx.x*256 + threadIdx.x;
  if (i >= total) return;
  dst[i] = (i < valid) ? f2bf(src[i]) : (u16)0;
}

// ---------------- LayerNorm: x [b][c][l] fp32 -> XNT [b][l][c] bf16 ----------------
__global__ void ln_kernel(const float* __restrict__ X, const float* __restrict__ lnw,
                          const float* __restrict__ lnb, u16* __restrict__ XNT) {
  int pos = blockIdx.x*256 + threadIdx.x;
  int b = pos >> 12, l = pos & (LSP-1);
  const float* xb = X + ((size_t)b*DIMC)*LSP + l;
  float sum=0.f, sq=0.f;
  for (int c=0;c<DIMC;c++){ float v=xb[(size_t)c*LSP]; sum+=v; sq+=v*v; }
  float mu = sum*(1.f/DIMC);
  float var = sq*(1.f/DIMC) - mu*mu;
  float rs = rsqrtf(var + 1e-5f);
  u16* ob = XNT + ((size_t)(b*LSP + l))*DIMC;
  for (int c0=0;c0<DIMC;c0+=8){
    u16x8 v8;
    #pragma unroll
    for(int j=0;j<8;j++){
      float v = xb[(size_t)(c0+j)*LSP];
      v8[j] = f2bf((v-mu)*rs*lnw[c0+j] + lnb[c0+j]);
    }
    *(u16x8*)&ob[c0] = v8;
  }
}

// ---------------- GEMM-ZT (MFMA): ZT[b][l][d] = XNT[l][c] x Wz[d][c]^T ----------------
__global__ void gemm_zt_mfma(const u16* __restrict__ W, const u16* __restrict__ Bm,
                             u16* __restrict__ ZT){
  __shared__ u16 As[128][32];
  __shared__ u16 Bs[128][32];
  int tid=threadIdx.x, w=tid>>6, lane=tid&63, l15=lane&15, quad=lane>>4;
  int b=blockIdx.z, m0=blockIdx.y*128, n0=blockIdx.x*128;  // m=l, n=d
  const u16* Ab = Bm + ((size_t)b*LSP + m0)*DIMC;          // XNT rows (l)
  f32x4 acc[4][4];
  #pragma unroll
  for(int i=0;i<4;i++)
    #pragma unroll
    for(int j=0;j<4;j++) acc[i][j] = (f32x4){0.f,0.f,0.f,0.f};
  for (int k0=0;k0<DIMC;k0+=32){
    __syncthreads();
    {
      int ch = tid*2;
      int r = ch>>2, o=(ch&3)*8;
      *(u16x8*)&As[r][o] = *(const u16x8*)&Ab[(size_t)r*DIMC + k0 + o];
      *(u16x8*)&Bs[r][o] = *(const u16x8*)&W[(size_t)(n0+r)*DIMC + k0 + o];
      ch++; r = ch>>2; o=(ch&3)*8;
      *(u16x8*)&As[r][o] = *(const u16x8*)&Ab[(size_t)r*DIMC + k0 + o];
      *(u16x8*)&Bs[r][o] = *(const u16x8*)&W[(size_t)(n0+r)*DIMC + k0 + o];
    }
    __syncthreads();
    int mrow = (w>>1)*64, ncol=(w&1)*64;
    u16x8 af[4], bfr[4];
    #pragma unroll
    for(int mt=0;mt<4;mt++) af[mt] = *(const u16x8*)&As[mrow+mt*16+l15][quad*8];
    #pragma unroll
    for(int nt=0;nt<4;nt++) bfr[nt] = *(const u16x8*)&Bs[ncol+nt*16+l15][quad*8];
    #pragma unroll
    for(int mt=0;mt<4;mt++)
      #pragma unroll
      for(int nt=0;nt<4;nt++)
        acc[mt][nt]=MFMA16(af[mt],bfr[nt],acc[mt][nt]);
  }
  #pragma unroll
  for(int mt=0;mt<4;mt++)
    #pragma unroll
    for(int nt=0;nt<4;nt++)
      #pragma unroll
      for(int r=0;r<4;r++){
        int l = m0 + (w>>1)*64 + mt*16 + quad*4 + r;
        int d = n0 + (w&1)*64 + nt*16 + l15;
        ZT[((size_t)b*LSP + l)*DINNER + d] = f2bf(acc[mt][nt][r]);
      }
}

// ---------------- GEMM-XBCDT (MFMA): rows 512..1279 of W, planar outputs --------------
__global__ void gemm_xbcdt_mfma(const u16* __restrict__ A, const u16* __restrict__ Bm,
                                u16* __restrict__ XBC, u16* __restrict__ DT){
  __shared__ u16 As[128][32];
  __shared__ u16 Bs[128][32];
  int tid=threadIdx.x, w=tid>>6, lane=tid&63, l15=lane&15, quad=lane>>4;
  int b=blockIdx.z, m0=DINNER + blockIdx.y*128, n0=blockIdx.x*128;
  const u16* Bb = Bm + ((size_t)b*LSP + n0)*DIMC;
  f32x4 acc[4][4];
  #pragma unroll
  for(int i=0;i<4;i++)
    #pragma unroll
    for(int j=0;j<4;j++) acc[i][j] = (f32x4){0.f,0.f,0.f,0.f};
  for (int k0=0;k0<DIMC;k0+=32){
    __syncthreads();
    {
      int ch = tid*2;
      int r = ch>>2, o=(ch&3)*8;
      *(u16x8*)&As[r][o] = *(const u16x8*)&A[(size_t)(m0+r)*DIMC + k0 + o];
      *(u16x8*)&Bs[r][o] = *(const u16x8*)&Bb[(size_t)r*DIMC + k0 + o];
      ch++; r = ch>>2; o=(ch&3)*8;
      *(u16x8*)&As[r][o] = *(const u16x8*)&A[(size_t)(m0+r)*DIMC + k0 + o];
      *(u16x8*)&Bs[r][o] = *(const u16x8*)&Bb[(size_t)r*DIMC + k0 + o];
    }
    __syncthreads();
    int mrow = (w>>1)*64, ncol=(w&1)*64;
    u16x8 af[4], bfr[4];
    #pragma unroll
    for(int mt=0;mt<4;mt++) af[mt] = *(const u16x8*)&As[mrow+mt*16+l15][quad*8];
    #pragma unroll
    for(int nt=0;nt<4;nt++) bfr[nt] = *(const u16x8*)&Bs[ncol+nt*16+l15][quad*8];
    #pragma unroll
    for(int mt=0;mt<4;mt++)
      #pragma unroll
      for(int nt=0;nt<4;nt++)
        acc[mt][nt]=MFMA16(af[mt],bfr[nt],acc[mt][nt]);
  }
  #pragma unroll
  for(int mt=0;mt<4;mt++)
    #pragma unroll
    for(int nt=0;nt<4;nt++)
      #pragma unroll
      for(int r=0;r<4;r++){
        int row = m0 + (w>>1)*64 + mt*16 + quad*4 + r;
        if (row>=DPROJ) continue;
        int col = n0 + (w&1)*64 + nt*16 + l15;
        u16 v = f2bf(acc[mt][nt][r]);
        if (row<DINNER+CONVDIM)   XBC[((size_t)b*CONVDIM+(row-DINNER))*LSP+col]=v;
        else                      DT[((size_t)b*NHEADS+(row-DINNER-CONVDIM))*LSP+col]=v;
      }
}

// ---------------- GEMM2 (MFMA): W2 [256x512 bf16] x YG [b,l,512] + x -> out fp32 ----
__global__ void gemm_out_mfma(const u16* __restrict__ A, const u16* __restrict__ Bm,
                              const float* __restrict__ Res, float* __restrict__ Out){
  __shared__ u16 As[128][32];
  __shared__ u16 Bs[128][32];
  int tid=threadIdx.x, w=tid>>6, lane=tid&63, l15=lane&15, quad=lane>>4;
  int b=blockIdx.z, m0=blockIdx.y*128, n0=blockIdx.x*128;
  const u16* Bb = Bm + ((size_t)b*LSP + n0)*DINNER;
  f32x4 acc[4][4];
  #pragma unroll
  for(int i=0;i<4;i++)
    #pragma unroll
    for(int j=0;j<4;j++) acc[i][j] = (f32x4){0.f,0.f,0.f,0.f};
  for (int k0=0;k0<DINNER;k0+=32){
    __syncthreads();
    {
      int ch = tid*2;
      int r = ch>>2, o=(ch&3)*8;
      *(u16x8*)&As[r][o] = *(const u16x8*)&A[(size_t)(m0+r)*DINNER + k0 + o];
      *(u16x8*)&Bs[r][o] = *(const u16x8*)&Bb[(size_t)r*DINNER + k0 + o];
      ch++; r = ch>>2; o=(ch&3)*8;
      *(u16x8*)&As[r][o] = *(const u16x8*)&A[(size_t)(m0+r)*DINNER + k0 + o];
      *(u16x8*)&Bs[r][o] = *(const u16x8*)&Bb[(size_t)r*DINNER + k0 + o];
    }
    __syncthreads();
    int mrow = (w>>1)*64, ncol=(w&1)*64;
    u16x8 af[4], bfr[4];
    #pragma unroll
    for(int mt=0;mt<4;mt++) af[mt] = *(const u16x8*)&As[mrow+mt*16+l15][quad*8];
    #pragma unroll
    for(int nt=0;nt<4;nt++) bfr[nt] = *(const u16x8*)&Bs[ncol+nt*16+l15][quad*8];
    #pragma unroll
    for(int mt=0;mt<4;mt++)
      #pragma unroll
      for(int nt=0;nt<4;nt++)
        acc[mt][nt]=MFMA16(af[mt],bfr[nt],acc[mt][nt]);
  }
  #pragma unroll
  for(int mt=0;mt<4;mt++)
    #pragma unroll
    for(int nt=0;nt<4;nt++)
      #pragma unroll
      for(int r=0;r<4;r++){
        int row = m0 + (w>>1)*64 + mt*16 + quad*4 + r;
        int col = n0 + (w&1)*64 + nt*16 + l15;
        size_t oi = ((size_t)b*DIMC+row)*LSP+col;
        Out[oi] = acc[mt][nt][r] + Res[oi];
      }
}

// ---------------- Depthwise 3x3 conv + bias + SiLU, IN-PLACE on XBC ----------------
__global__ void conv_kernel(u16* __restrict__ XBC, const float* __restrict__ CW,
                            const float* __restrict__ CB){
  int ch = blockIdx.x, b = blockIdx.y, tid = threadIdx.x;
  __shared__ float plane[66*66];
  u16* base = XBC + ((size_t)b*CONVDIM + ch)*LSP;
  for (int idx=tid; idx<66*66; idx+=256){
    int yy = idx/66 - 1, xx = idx%66 - 1;
    float v = 0.f;
    if (yy>=0 && yy<64 && xx>=0 && xx<64) v = bf2f(base[yy*64+xx]);
    plane[idx] = v;
  }
  float wg[9];
  #pragma unroll
  for (int t=0;t<9;t++) wg[t] = CW[ch*9+t];
  float bias = CB[ch];
  __syncthreads();
  for (int r=0;r<16;r++){
    int pix = tid + r*256;
    int y = pix>>6, x = pix&63;
    float s=0.f;
    #pragma unroll
    for(int dy=0;dy<3;dy++)
      #pragma unroll
      for(int dx=0;dx<3;dx++) s += plane[(y+dy)*66 + x+dx]*wg[dy*3+dx];
    base[pix] = f2bf(siluf(s + bias));
  }
}

// ---------------- SSD states (MFMA): states_T[p][n] = sum_t Xdtw[t][p]*B[t][n] ------
__global__ __launch_bounds__(256,2) void ssd_states_mfma(
    const u16* __restrict__ DT, const u16* __restrict__ XBC,
    const float* __restrict__ A_log, const float* __restrict__ dt_bias,
    float* __restrict__ STATES, float* __restrict__ DASUM){
  int c=blockIdx.x, h=blockIdx.y, b=blockIdx.z;
  int tid=threadIdx.x, w=tid>>6, lane=tid&63, l15=lane&15, quad=lane>>4;
  __shared__ float acs[CHUNK];
  __shared__ float wdt[CHUNK];
  __shared__ u16 Xw[64][136];
  __shared__ u16 Bn[64][136];
  float raw = bf2f(DT[((size_t)b*NHEADS+h)*LSP + c*CHUNK + tid]);
  float dtv = softplusf(raw + dt_bias[h]);
  float Ah = -expf(A_log[h]);
  acs[tid]=dtv*Ah;
  __syncthreads();
  for(int o=1;o<256;o<<=1){
    float add=(tid>=o)?acs[tid-o]:0.f;
    __syncthreads(); acs[tid]+=add; __syncthreads();
  }
  float atot = acs[CHUNK-1];
  if(tid==0) DASUM[((size_t)b*NHEADS+h)*NCHUNK+c]=atot;
  wdt[tid] = dtv*expf(atot-acs[tid]);
  __syncthreads();
  f32x4 acc[4];
  #pragma unroll
  for(int i=0;i<4;i++) acc[i] = (f32x4){0.f,0.f,0.f,0.f};
  size_t cb = (size_t)c*CHUNK;
  for(int th=0; th<2; th++){
    __syncthreads();
    {
      int n=tid&63, q4=tid>>6;
      const u16* Xg = XBC + ((size_t)b*CONVDIM + h*HEADDIM + n)*LSP + cb + th*128;
      const u16* Bg = XBC + ((size_t)b*CONVDIM + DINNER + n)*LSP + cb + th*128;
      #pragma unroll
      for(int i=0;i<4;i++){
        int o = q4*32+i*8;
        u16x8 v = *(const u16x8*)&Xg[o];
        u16x8 wv;
        #pragma unroll
        for(int j=0;j<8;j++) wv[j]=f2bf(bf2f(v[j])*wdt[th*128+o+j]);
        *(u16x8*)&Xw[n][o]=wv;
        *(u16x8*)&Bn[n][o] = *(const u16x8*)&Bg[o];
      }
    }
    __syncthreads();
    #pragma unroll
    for(int k8=0;k8<4;k8++){
      u16x8 a = *(const u16x8*)&Xw[w*16+l15][k8*32+quad*8];
      #pragma unroll
      for(int nt=0;nt<4;nt++){
        u16x8 bb = *(const u16x8*)&Bn[nt*16+l15][k8*32+quad*8];
        acc[nt]=MFMA16(a,bb,acc[nt]);
      }
    }
  }
  float* dst = STATES + (((size_t)b*NHEADS+h)*NCHUNK+c)*4096;
  #pragma unroll
  for(int nt=0;nt<4;nt++)
    #pragma unroll
    for(int r=0;r<4;r++)
      dst[(w*16+quad*4+r)*64 + nt*16+l15] = acc[nt][r];
}

// ---------------- inter-chunk scan -> PREVB bf16 [p][n] per (b,h,c) ----------------
__global__ void ssd_scan_kernel(const float* __restrict__ STATES, const float* __restrict__ DASUM,
                                u16* __restrict__ PREVB){
  int g = blockIdx.x, h = blockIdx.y, b = blockIdx.z, tid = threadIdx.x;
  int e = g*256 + tid;
  size_t hb = (size_t)b*NHEADS + h;
  size_t base = hb*NCHUNK*4096 + e;
  float s = 0.f;
  for (int cc=0;cc<NCHUNK;cc++){
    PREVB[base + (size_t)cc*4096] = f2bf(s);
    s = s*expf(DASUM[hb*NCHUNK + cc]) + STATES[base + (size_t)cc*4096];
  }
}

// ---------------- SSD Y (MFMA, flash-style): one 64-t band per block ----------------
__global__ __launch_bounds__(256,2) void ssd_y_mfma(
    const u16* __restrict__ DT, const u16* __restrict__ XBC,
    const float* __restrict__ A_log, const float* __restrict__ dt_bias,
    const float* __restrict__ Dp, const u16* __restrict__ PREVB,
    u16* __restrict__ YG){
  int bx = blockIdx.x; int c = bx>>2, tb = bx&3;
  int h = blockIdx.y, b = blockIdx.z;
  int tid=threadIdx.x, w=tid>>6, lane=tid&63, l15=lane&15, quad=lane>>4;
  __shared__ float acs[CHUNK];
  __shared__ float dtb[CHUNK];
  __shared__ u16 Ct[64][72];
  __shared__ u16 Xt[64][264];
  __shared__ u16 Bsb[64][72];
  __shared__ u16 P[4][16][72];
  float raw = bf2f(DT[((size_t)b*NHEADS+h)*LSP + c*CHUNK + tid]);
  float dtv = softplusf(raw + dt_bias[h]);
  float Ah = -expf(A_log[h]);
  dtb[tid]=dtv; acs[tid]=dtv*Ah;
  __syncthreads();
  for(int o=1;o<256;o<<=1){
    float add=(tid>=o)?acs[tid-o]:0.f;
    __syncthreads(); acs[tid]+=add; __syncthreads();
  }
  {
    int n = tid&63, q4 = tid>>6;
    const u16* Cg = XBC + ((size_t)b*CONVDIM + DINNER + DSTATE + n)*LSP + (size_t)c*CHUNK + tb*64;
    #pragma unroll
    for(int i=0;i<2;i++){
      u16x8 v = *(const u16x8*)&Cg[q4*16+i*8];
      #pragma unroll
      for(int j=0;j<8;j++) Ct[q4*16+i*8+j][n]=v[j];
    }
    const u16* Xg = XBC + ((size_t)b*CONVDIM + h*HEADDIM + n)*LSP + (size_t)c*CHUNK;
    int smax = (tb+1)*64;
    int s0 = q4*64;
    if (s0 < smax){
      #pragma unroll
      for(int i=0;i<8;i++){
        u16x8 v = *(const u16x8*)&Xg[s0+i*8];
        u16x8 wv;
        #pragma unroll
        for(int j=0;j<8;j++) wv[j] = f2bf(bf2f(v[j])*dtb[s0+i*8+j]);
        *(u16x8*)&Xt[n][s0+i*8] = wv;
      }
    }
  }
  __syncthreads();
  f32x4 Y[4];
  #pragma unroll
  for(int i=0;i<4;i++) Y[i]=(f32x4){0.f,0.f,0.f,0.f};
  int trow = w*16 + l15;
  u16x8 ca0 = *(const u16x8*)&Ct[trow][quad*8];
  u16x8 ca1 = *(const u16x8*)&Ct[trow][32+quad*8];
  {
    float ea = expf(acs[tb*64 + trow]);
    u16x8 a0 = fscale(ca0, ea);
    u16x8 a1 = fscale(ca1, ea);
    const u16* Pg = PREVB + (((size_t)b*NHEADS+h)*NCHUNK + c)*4096;
    #pragma unroll
    for(int pt=0;pt<4;pt++){
      u16x8 b0 = *(const u16x8*)&Pg[(pt*16+l15)*64 + quad*8];
      u16x8 b1 = *(const u16x8*)&Pg[(pt*16+l15)*64 + 32 + quad*8];
      Y[pt]=MFMA16(a0,b0,Y[pt]);
      Y[pt]=MFMA16(a1,b1,Y[pt]);
    }
  }
  for(int sb=0; sb<=tb; sb++){
    __syncthreads();
    {
      int n=tid&63, q4=tid>>6;
      const u16* Bg = XBC + ((size_t)b*CONVDIM + DINNER + n)*LSP + (size_t)c*CHUNK + sb*64;
      #pragma unroll
      for(int i=0;i<2;i++){
        u16x8 v = *(const u16x8*)&Bg[q4*16+i*8];
        #pragma unroll
        for(int j=0;j<8;j++) Bsb[q4*16+i*8+j][n]=v[j];
      }
    }
    __syncthreads();
    f32x4 S[4];
    #pragma unroll
    for(int st=0;st<4;st++) S[st]=(f32x4){0.f,0.f,0.f,0.f};
    #pragma unroll
    for(int st=0;st<4;st++){
      u16x8 b0 = *(const u16x8*)&Bsb[st*16+l15][quad*8];
      u16x8 b1 = *(const u16x8*)&Bsb[st*16+l15][32+quad*8];
      S[st]=MFMA16(ca0,b0,S[st]);
      S[st]=MFMA16(ca1,b1,S[st]);
    }
    int tloc = tb*64 + w*16 + quad*4;
    #pragma unroll
    for(int st=0;st<4;st++){
      int s = sb*64 + st*16 + l15;
      float as = acs[s];
      #pragma unroll
      for(int r=0;r<4;r++){
        int t = tloc + r;
        float arg = acs[t]-as;
        float e = (s<=t)? expf(arg) : 0.f;
        P[w][quad*4+r][st*16+l15] = f2bf(S[st][r]*e);
      }
    }
    u16x8 p0 = *(const u16x8*)&P[w][l15][quad*8];
    u16x8 p1 = *(const u16x8*)&P[w][l15][32+quad*8];
    #pragma unroll
    for(int pt=0;pt<4;pt++){
      u16x8 x0 = *(const u16x8*)&Xt[pt*16+l15][sb*64+quad*8];
      u16x8 x1 = *(const u16x8*)&Xt[pt*16+l15][sb*64+32+quad*8];
      Y[pt]=MFMA16(p0,x0,Y[pt]);
      Y[pt]=MFMA16(p1,x1,Y[pt]);
    }
  }
  float Dh = Dp[h];
  size_t lbase = (size_t)b*LSP + c*CHUNK + tb*64;
  #pragma unroll
  for(int pt=0;pt<4;pt++){
    #pragma unroll
    for(int r=0;r<4;r++){
      int tl = w*16 + quad*4 + r;
      int p = pt*16 + l15;
      float xdt = bf2f(Xt[p][tb*64 + tl]);
      float xs = xdt / dtb[tb*64 + tl];
      float y = Y[pt][r] + Dh*xs;
      YG[(lbase + tl)*DINNER + h*HEADDIM + p] = f2bf(y);
    }
  }
}

// ---------------- gate (silu(z)) + RMSNorm, IN-PLACE on YG [l][d]; ZT [l][d] --------
__global__ void gate_kernel(u16* __restrict__ YG, const u16* __restrict__ ZT,
                            const float* __restrict__ rmsw){
  __shared__ float rw[DINNER];
  int tid = threadIdx.x;
  for (int i=tid;i<DINNER;i+=256) rw[i]=rmsw[i];
  __syncthreads();
  int wv = tid>>6, lane = tid&63;
  size_t row = (size_t)blockIdx.x*4 + wv;      // global (b*LSP+l)
  size_t base = row*DINNER + lane*8;
  u16x8 yv = *(const u16x8*)&YG[base];
  u16x8 zv = *(const u16x8*)&ZT[base];
  float g[8]; float sq=0.f;
  #pragma unroll
  for(int j=0;j<8;j++){
    g[j] = bf2f(yv[j]) * siluf(bf2f(zv[j]));
    sq += g[j]*g[j];
  }
  #pragma unroll
  for(int o=32;o>0;o>>=1) sq += __shfl_xor(sq, o, 64);
  float rinv = rsqrtf(sq*(1.f/DINNER) + 1e-5f);
  u16x8 ov;
  #pragma unroll
  for(int j=0;j<8;j++) ov[j] = f2bf(g[j]*rinv*rw[lane*8+j]);
  *(u16x8*)&YG[base] = ov;
}

extern "C" void kernel_launch(void* const* d_in, const int* in_sizes, int n_in,
                              void* d_out, int out_size, void* d_ws, size_t ws_size,
                              hipStream_t stream) {
  const float* x     = (const float*)d_in[0];
  const float* lnw   = (const float*)d_in[1];
  const float* lnb   = (const float*)d_in[2];
  const float* inpw  = (const float*)d_in[3];
  const float* convw = (const float*)d_in[4];
  const float* convb = (const float*)d_in[5];
  const float* alog  = (const float*)d_in[6];
  const float* Dp    = (const float*)d_in[7];
  const float* dtbi  = (const float*)d_in[8];
  const float* rmsw  = (const float*)d_in[9];
  const float* outw  = (const float*)d_in[10];
  float* out = (float*)d_out;

  char* ws = (char*)d_ws;
  size_t off = 0;
  auto alloc = [&](size_t bytes)->void*{ void* p = ws+off; off += (bytes+255)&~(size_t)255; return p; };
  u16*   WPIN   = (u16*)  alloc((size_t)MPAD*DIMC*2);
  u16*   WPOUT  = (u16*)  alloc((size_t)DIMC*DINNER*2);
  char*  RA     = (char*) alloc((size_t)BATCH*NHEADS*NCHUNK*4096*4);
  u16*   XNT    = (u16*)RA;
  float* STATES = (float*)RA;
  u16*   ZT     = (u16*)  alloc((size_t)BATCH*LSP*DINNER*2);
  u16*   XBC    = (u16*)  alloc((size_t)BATCH*CONVDIM*LSP*2);
  u16*   DTb    = (u16*)  alloc((size_t)BATCH*NHEADS*LSP*2);
  u16*   PREVB  = (u16*)  alloc((size_t)BATCH*NHEADS*NCHUNK*4096*2);
  float* DASUM  = (float*)alloc((size_t)BATCH*NHEADS*NCHUNK*4);
  u16*   YG     = (u16*)  alloc((size_t)BATCH*LSP*DINNER*2);

  convert_w<<<(MPAD*DIMC+255)/256,256,0,stream>>>(inpw, WPIN, MPAD*DIMC, DPROJ*DIMC);
  convert_w<<<(DIMC*DINNER+255)/256,256,0,stream>>>(outw, WPOUT, DIMC*DINNER, DIMC*DINNER);
  ln_kernel<<<dim3(BATCH*LSP/256),256,0,stream>>>(x,lnw,lnb,XNT);
  gemm_zt_mfma<<<dim3(DINNER/128,LSP/128,BATCH),256,0,stream>>>(WPIN, XNT, ZT);
  gemm_xbcdt_mfma<<<dim3(LSP/128,(MPAD-DINNER)/128,BATCH),256,0,stream>>>(WPIN, XNT, XBC, DTb);
  conv_kernel<<<dim3(CONVDIM,BATCH),256,0,stream>>>(XBC, convw, convb);
  ssd_states_mfma<<<dim3(NCHUNK,NHEADS,BATCH),256,0,stream>>>(DTb,XBC,alog,dtbi,STATES,DASUM);
  ssd_scan_kernel<<<dim3(16,NHEADS,BATCH),256,0,stream>>>(STATES,DASUM,PREVB);
  ssd_y_mfma<<<dim3(NCHUNK*4,NHEADS,BATCH),256,0,stream>>>(DTb,XBC,alog,dtbi,Dp,PREVB,YG);
  gate_kernel<<<dim3(BATCH*LSP/4),256,0,stream>>>(YG,ZT,rmsw);
  gemm_out_mfma<<<dim3(LSP/128,DIMC/128,BATCH),256,0,stream>>>(WPOUT, YG, x, out);
}

// Round 7
// 385.162 us; speedup vs baseline: 4.0938x; 1.1443x over previous
//
#include <hip/hip_runtime.h>
#include <hip/hip_bf16.h>
#include <math.h>

#define DIMC   256
#define LSP    4096
#define BATCH  8
#define DINNER 512
#define NHEADS 8
#define HEADDIM 64
#define DSTATE 64
#define CONVDIM 640
#define DPROJ  1160
#define MPAD   1280
#define CHUNK  256
#define NCHUNK 16

typedef unsigned short u16;
typedef __attribute__((ext_vector_type(8))) unsigned short u16x8;
typedef __attribute__((ext_vector_type(8))) short s16x8;
typedef __attribute__((ext_vector_type(4))) float f32x4;

#define MFMA16(a,b,c) __builtin_amdgcn_mfma_f32_16x16x32_bf16((s16x8)(a),(s16x8)(b),(c),0,0,0)

__device__ __forceinline__ float bf2f(u16 u){ return __uint_as_float(((unsigned int)u)<<16); }
__device__ __forceinline__ u16 f2bf(float f){
  unsigned int x = __float_as_uint(f);
  unsigned int r = (x + 0x7fffu + ((x>>16)&1u)) >> 16;
  return (u16)r;
}
__device__ __forceinline__ float softplusf(float x){ return (x > 20.f) ? x : log1pf(expf(x)); }
__device__ __forceinline__ float siluf(float x){ return x / (1.f + expf(-x)); }
__device__ __forceinline__ u16x8 fscale(u16x8 v, float s){
  u16x8 r;
  #pragma unroll
  for(int j=0;j<8;j++) r[j] = f2bf(bf2f(v[j])*s);
  return r;
}

// ---------------- weight fp32 -> bf16 (with trailing-row zero pad) ----------------
__global__ void convert_w(const float* __restrict__ src, u16* __restrict__ dst,
                          int total, int valid){
  int i = blockIdx.x*256 + threadIdx.x;
  if (i >= total) return;
  dst[i] = (i < valid) ? f2bf(src[i]) : (u16)0;
}

// ---------------- LayerNorm: x [b][c][l] fp32 -> XNT [b][l][c] bf16 ----------------
__global__ void ln_kernel(const float* __restrict__ X, const float* __restrict__ lnw,
                          const float* __restrict__ lnb, u16* __restrict__ XNT) {
  int pos = blockIdx.x*256 + threadIdx.x;
  int b = pos >> 12, l = pos & (LSP-1);
  const float* xb = X + ((size_t)b*DIMC)*LSP + l;
  float sum=0.f, sq=0.f;
  for (int c=0;c<DIMC;c++){ float v=xb[(size_t)c*LSP]; sum+=v; sq+=v*v; }
  float mu = sum*(1.f/DIMC);
  float var = sq*(1.f/DIMC) - mu*mu;
  float rs = rsqrtf(var + 1e-5f);
  u16* ob = XNT + ((size_t)(b*LSP + l))*DIMC;
  for (int c0=0;c0<DIMC;c0+=8){
    u16x8 v8;
    #pragma unroll
    for(int j=0;j<8;j++){
      float v = xb[(size_t)(c0+j)*LSP];
      v8[j] = f2bf((v-mu)*rs*lnw[c0+j] + lnb[c0+j]);
    }
    *(u16x8*)&ob[c0] = v8;
  }
}

// ---------------- GEMM-ZT (MFMA): ZT[b][l][d] = XNT[l][c] x Wz[d][c]^T ----------------
__global__ void gemm_zt_mfma(const u16* __restrict__ W, const u16* __restrict__ Bm,
                             u16* __restrict__ ZT){
  __shared__ u16 As[128][32];
  __shared__ u16 Bs[128][32];
  int tid=threadIdx.x, w=tid>>6, lane=tid&63, l15=lane&15, quad=lane>>4;
  int b=blockIdx.z, m0=blockIdx.y*128, n0=blockIdx.x*128;  // m=l, n=d
  const u16* Ab = Bm + ((size_t)b*LSP + m0)*DIMC;
  f32x4 acc[4][4];
  #pragma unroll
  for(int i=0;i<4;i++)
    #pragma unroll
    for(int j=0;j<4;j++) acc[i][j] = (f32x4){0.f,0.f,0.f,0.f};
  for (int k0=0;k0<DIMC;k0+=32){
    __syncthreads();
    {
      int ch = tid*2;
      int r = ch>>2, o=(ch&3)*8;
      *(u16x8*)&As[r][o] = *(const u16x8*)&Ab[(size_t)r*DIMC + k0 + o];
      *(u16x8*)&Bs[r][o] = *(const u16x8*)&W[(size_t)(n0+r)*DIMC + k0 + o];
      ch++; r = ch>>2; o=(ch&3)*8;
      *(u16x8*)&As[r][o] = *(const u16x8*)&Ab[(size_t)r*DIMC + k0 + o];
      *(u16x8*)&Bs[r][o] = *(const u16x8*)&W[(size_t)(n0+r)*DIMC + k0 + o];
    }
    __syncthreads();
    int mrow = (w>>1)*64, ncol=(w&1)*64;
    u16x8 af[4], bfr[4];
    #pragma unroll
    for(int mt=0;mt<4;mt++) af[mt] = *(const u16x8*)&As[mrow+mt*16+l15][quad*8];
    #pragma unroll
    for(int nt=0;nt<4;nt++) bfr[nt] = *(const u16x8*)&Bs[ncol+nt*16+l15][quad*8];
    #pragma unroll
    for(int mt=0;mt<4;mt++)
      #pragma unroll
      for(int nt=0;nt<4;nt++)
        acc[mt][nt]=MFMA16(af[mt],bfr[nt],acc[mt][nt]);
  }
  #pragma unroll
  for(int mt=0;mt<4;mt++)
    #pragma unroll
    for(int nt=0;nt<4;nt++)
      #pragma unroll
      for(int r=0;r<4;r++){
        int l = m0 + (w>>1)*64 + mt*16 + quad*4 + r;
        int d = n0 + (w&1)*64 + nt*16 + l15;
        ZT[((size_t)b*LSP + l)*DINNER + d] = f2bf(acc[mt][nt][r]);
      }
}

// ---------------- GEMM-XBCDT (MFMA): rows 512..1279 of W, planar outputs --------------
__global__ void gemm_xbcdt_mfma(const u16* __restrict__ A, const u16* __restrict__ Bm,
                                u16* __restrict__ XBC, u16* __restrict__ DT){
  __shared__ u16 As[128][32];
  __shared__ u16 Bs[128][32];
  int tid=threadIdx.x, w=tid>>6, lane=tid&63, l15=lane&15, quad=lane>>4;
  int b=blockIdx.z, m0=DINNER + blockIdx.y*128, n0=blockIdx.x*128;
  const u16* Bb = Bm + ((size_t)b*LSP + n0)*DIMC;
  f32x4 acc[4][4];
  #pragma unroll
  for(int i=0;i<4;i++)
    #pragma unroll
    for(int j=0;j<4;j++) acc[i][j] = (f32x4){0.f,0.f,0.f,0.f};
  for (int k0=0;k0<DIMC;k0+=32){
    __syncthreads();
    {
      int ch = tid*2;
      int r = ch>>2, o=(ch&3)*8;
      *(u16x8*)&As[r][o] = *(const u16x8*)&A[(size_t)(m0+r)*DIMC + k0 + o];
      *(u16x8*)&Bs[r][o] = *(const u16x8*)&Bb[(size_t)r*DIMC + k0 + o];
      ch++; r = ch>>2; o=(ch&3)*8;
      *(u16x8*)&As[r][o] = *(const u16x8*)&A[(size_t)(m0+r)*DIMC + k0 + o];
      *(u16x8*)&Bs[r][o] = *(const u16x8*)&Bb[(size_t)r*DIMC + k0 + o];
    }
    __syncthreads();
    int mrow = (w>>1)*64, ncol=(w&1)*64;
    u16x8 af[4], bfr[4];
    #pragma unroll
    for(int mt=0;mt<4;mt++) af[mt] = *(const u16x8*)&As[mrow+mt*16+l15][quad*8];
    #pragma unroll
    for(int nt=0;nt<4;nt++) bfr[nt] = *(const u16x8*)&Bs[ncol+nt*16+l15][quad*8];
    #pragma unroll
    for(int mt=0;mt<4;mt++)
      #pragma unroll
      for(int nt=0;nt<4;nt++)
        acc[mt][nt]=MFMA16(af[mt],bfr[nt],acc[mt][nt]);
  }
  #pragma unroll
  for(int mt=0;mt<4;mt++)
    #pragma unroll
    for(int nt=0;nt<4;nt++)
      #pragma unroll
      for(int r=0;r<4;r++){
        int row = m0 + (w>>1)*64 + mt*16 + quad*4 + r;
        if (row>=DPROJ) continue;
        int col = n0 + (w&1)*64 + nt*16 + l15;
        u16 v = f2bf(acc[mt][nt][r]);
        if (row<DINNER+CONVDIM)   XBC[((size_t)b*CONVDIM+(row-DINNER))*LSP+col]=v;
        else                      DT[((size_t)b*NHEADS+(row-DINNER-CONVDIM))*LSP+col]=v;
      }
}

// ---------------- GEMM2 (MFMA): W2 [256x512 bf16] x YG [b,l,512] + x -> out fp32 ----
__global__ void gemm_out_mfma(const u16* __restrict__ A, const u16* __restrict__ Bm,
                              const float* __restrict__ Res, float* __restrict__ Out){
  __shared__ u16 As[128][32];
  __shared__ u16 Bs[128][32];
  int tid=threadIdx.x, w=tid>>6, lane=tid&63, l15=lane&15, quad=lane>>4;
  int b=blockIdx.z, m0=blockIdx.y*128, n0=blockIdx.x*128;
  const u16* Bb = Bm + ((size_t)b*LSP + n0)*DINNER;
  f32x4 acc[4][4];
  #pragma unroll
  for(int i=0;i<4;i++)
    #pragma unroll
    for(int j=0;j<4;j++) acc[i][j] = (f32x4){0.f,0.f,0.f,0.f};
  for (int k0=0;k0<DINNER;k0+=32){
    __syncthreads();
    {
      int ch = tid*2;
      int r = ch>>2, o=(ch&3)*8;
      *(u16x8*)&As[r][o] = *(const u16x8*)&A[(size_t)(m0+r)*DINNER + k0 + o];
      *(u16x8*)&Bs[r][o] = *(const u16x8*)&Bb[(size_t)r*DINNER + k0 + o];
      ch++; r = ch>>2; o=(ch&3)*8;
      *(u16x8*)&As[r][o] = *(const u16x8*)&A[(size_t)(m0+r)*DINNER + k0 + o];
      *(u16x8*)&Bs[r][o] = *(const u16x8*)&Bb[(size_t)r*DINNER + k0 + o];
    }
    __syncthreads();
    int mrow = (w>>1)*64, ncol=(w&1)*64;
    u16x8 af[4], bfr[4];
    #pragma unroll
    for(int mt=0;mt<4;mt++) af[mt] = *(const u16x8*)&As[mrow+mt*16+l15][quad*8];
    #pragma unroll
    for(int nt=0;nt<4;nt++) bfr[nt] = *(const u16x8*)&Bs[ncol+nt*16+l15][quad*8];
    #pragma unroll
    for(int mt=0;mt<4;mt++)
      #pragma unroll
      for(int nt=0;nt<4;nt++)
        acc[mt][nt]=MFMA16(af[mt],bfr[nt],acc[mt][nt]);
  }
  #pragma unroll
  for(int mt=0;mt<4;mt++)
    #pragma unroll
    for(int nt=0;nt<4;nt++)
      #pragma unroll
      for(int r=0;r<4;r++){
        int row = m0 + (w>>1)*64 + mt*16 + quad*4 + r;
        int col = n0 + (w&1)*64 + nt*16 + l15;
        size_t oi = ((size_t)b*DIMC+row)*LSP+col;
        Out[oi] = acc[mt][nt][r] + Res[oi];
      }
}

// ---------------- Depthwise 3x3 conv + bias + SiLU, IN-PLACE on XBC ----------------
__global__ void conv_kernel(u16* __restrict__ XBC, const float* __restrict__ CW,
                            const float* __restrict__ CB){
  int ch = blockIdx.x, b = blockIdx.y, tid = threadIdx.x;
  __shared__ float plane[66*66];
  u16* base = XBC + ((size_t)b*CONVDIM + ch)*LSP;
  for (int idx=tid; idx<66*66; idx+=256){
    int yy = idx/66 - 1, xx = idx%66 - 1;
    float v = 0.f;
    if (yy>=0 && yy<64 && xx>=0 && xx<64) v = bf2f(base[yy*64+xx]);
    plane[idx] = v;
  }
  float wg[9];
  #pragma unroll
  for (int t=0;t<9;t++) wg[t] = CW[ch*9+t];
  float bias = CB[ch];
  __syncthreads();
  for (int r=0;r<16;r++){
    int pix = tid + r*256;
    int y = pix>>6, x = pix&63;
    float s=0.f;
    #pragma unroll
    for(int dy=0;dy<3;dy++)
      #pragma unroll
      for(int dx=0;dx<3;dx++) s += plane[(y+dy)*66 + x+dx]*wg[dy*3+dx];
    base[pix] = f2bf(siluf(s + bias));
  }
}

// ---------------- SSD pre: dt softplus + per-chunk cumsum, done ONCE ----------------
__global__ void ssd_pre_kernel(const u16* __restrict__ DT, const float* __restrict__ A_log,
                               const float* __restrict__ dt_bias, float* __restrict__ ACS,
                               float* __restrict__ DTV, float* __restrict__ DASUM){
  int c=blockIdx.x, h=blockIdx.y, b=blockIdx.z, tid=threadIdx.x;
  __shared__ float acs[CHUNK];
  size_t base = ((size_t)b*NHEADS+h)*LSP + c*CHUNK + tid;
  float raw = bf2f(DT[base]);
  float dtv = softplusf(raw + dt_bias[h]);
  float Ah = -expf(A_log[h]);
  acs[tid] = dtv*Ah;
  __syncthreads();
  for(int o=1;o<256;o<<=1){
    float add=(tid>=o)?acs[tid-o]:0.f;
    __syncthreads(); acs[tid]+=add; __syncthreads();
  }
  ACS[base] = acs[tid];
  DTV[base] = dtv;
  if (tid==CHUNK-1) DASUM[((size_t)b*NHEADS+h)*NCHUNK+c] = acs[tid];
}

// ---------------- SSD states (MFMA): states_T[p][n] = sum_t Xdtw[t][p]*B[t][n] ------
__global__ __launch_bounds__(256,4) void ssd_states_mfma(
    const float* __restrict__ ACS, const float* __restrict__ DTV,
    const float* __restrict__ DASUM, const u16* __restrict__ XBC,
    float* __restrict__ STATES){
  int c=blockIdx.x, h=blockIdx.y, b=blockIdx.z;
  int tid=threadIdx.x, w=tid>>6, lane=tid&63, l15=lane&15, quad=lane>>4;
  __shared__ float wdt[CHUNK];
  __shared__ u16 Xw[64][136];
  __shared__ u16 Bn[64][136];
  {
    size_t base = ((size_t)b*NHEADS+h)*LSP + c*CHUNK + tid;
    float atot = DASUM[((size_t)b*NHEADS+h)*NCHUNK+c];
    wdt[tid] = DTV[base]*expf(atot - ACS[base]);
  }
  __syncthreads();
  f32x4 acc[4];
  #pragma unroll
  for(int i=0;i<4;i++) acc[i] = (f32x4){0.f,0.f,0.f,0.f};
  size_t cb = (size_t)c*CHUNK;
  for(int th=0; th<2; th++){
    __syncthreads();
    {
      int n=tid&63, q4=tid>>6;
      const u16* Xg = XBC + ((size_t)b*CONVDIM + h*HEADDIM + n)*LSP + cb + th*128;
      const u16* Bg = XBC + ((size_t)b*CONVDIM + DINNER + n)*LSP + cb + th*128;
      #pragma unroll
      for(int i=0;i<4;i++){
        int o = q4*32+i*8;
        u16x8 v = *(const u16x8*)&Xg[o];
        u16x8 wv;
        #pragma unroll
        for(int j=0;j<8;j++) wv[j]=f2bf(bf2f(v[j])*wdt[th*128+o+j]);
        *(u16x8*)&Xw[n][o]=wv;
        *(u16x8*)&Bn[n][o] = *(const u16x8*)&Bg[o];
      }
    }
    __syncthreads();
    #pragma unroll
    for(int k8=0;k8<4;k8++){
      u16x8 a = *(const u16x8*)&Xw[w*16+l15][k8*32+quad*8];
      #pragma unroll
      for(int nt=0;nt<4;nt++){
        u16x8 bb = *(const u16x8*)&Bn[nt*16+l15][k8*32+quad*8];
        acc[nt]=MFMA16(a,bb,acc[nt]);
      }
    }
  }
  float* dst = STATES + (((size_t)b*NHEADS+h)*NCHUNK+c)*4096;
  #pragma unroll
  for(int nt=0;nt<4;nt++)
    #pragma unroll
    for(int r=0;r<4;r++)
      dst[(w*16+quad*4+r)*64 + nt*16+l15] = acc[nt][r];
}

// ---------------- inter-chunk scan -> PREVB bf16 [p][n] per (b,h,c) ----------------
__global__ void ssd_scan_kernel(const float* __restrict__ STATES, const float* __restrict__ DASUM,
                                u16* __restrict__ PREVB){
  int g = blockIdx.x, h = blockIdx.y, b = blockIdx.z, tid = threadIdx.x;
  int e = g*256 + tid;
  size_t hb = (size_t)b*NHEADS + h;
  size_t base = hb*NCHUNK*4096 + e;
  float s = 0.f;
  for (int cc=0;cc<NCHUNK;cc++){
    PREVB[base + (size_t)cc*4096] = f2bf(s);
    s = s*expf(DASUM[hb*NCHUNK + cc]) + STATES[base + (size_t)cc*4096];
  }
}

// ---------------- SSD Y (MFMA, flash-style): one 64-t band per block, 4 blk/CU ------
__global__ __launch_bounds__(256,4) void ssd_y_mfma(
    const float* __restrict__ ACS, const float* __restrict__ DTV,
    const u16* __restrict__ XBC, const float* __restrict__ Dp,
    const u16* __restrict__ PREVB, u16* __restrict__ YG){
  int bx = blockIdx.x; int c = bx>>2, tb = bx&3;
  int h = blockIdx.y, b = blockIdx.z;
  int tid=threadIdx.x, w=tid>>6, lane=tid&63, l15=lane&15, quad=lane>>4;
  __shared__ float acs[CHUNK];
  __shared__ float dtv[CHUNK];
  __shared__ u16 Ct[64][72];
  __shared__ u16 Bsb[64][72];
  __shared__ u16 Xsb[64][72];
  __shared__ u16 P[4][16][72];
  {
    size_t base = ((size_t)b*NHEADS+h)*LSP + c*CHUNK + tid;
    acs[tid] = ACS[base];
    dtv[tid] = DTV[base];
  }
  // stage C band [64t][64n] (transpose)
  {
    int n = tid&63, q4 = tid>>6;
    const u16* Cg = XBC + ((size_t)b*CONVDIM + DINNER + DSTATE + n)*LSP + (size_t)c*CHUNK + tb*64;
    #pragma unroll
    for(int i=0;i<2;i++){
      u16x8 v = *(const u16x8*)&Cg[q4*16+i*8];
      #pragma unroll
      for(int j=0;j<8;j++) Ct[q4*16+i*8+j][n]=v[j];
    }
  }
  __syncthreads();
  f32x4 Y[4];
  #pragma unroll
  for(int i=0;i<4;i++) Y[i]=(f32x4){0.f,0.f,0.f,0.f};
  int trow = w*16 + l15;
  u16x8 ca0 = *(const u16x8*)&Ct[trow][quad*8];
  u16x8 ca1 = *(const u16x8*)&Ct[trow][32+quad*8];
  // Y_off = (exp(acs[t]) * C) . prev
  {
    float ea = expf(acs[tb*64 + trow]);
    u16x8 a0 = fscale(ca0, ea);
    u16x8 a1 = fscale(ca1, ea);
    const u16* Pg = PREVB + (((size_t)b*NHEADS+h)*NCHUNK + c)*4096;
    #pragma unroll
    for(int pt=0;pt<4;pt++){
      u16x8 b0 = *(const u16x8*)&Pg[(pt*16+l15)*64 + quad*8];
      u16x8 b1 = *(const u16x8*)&Pg[(pt*16+l15)*64 + 32 + quad*8];
      Y[pt]=MFMA16(a0,b0,Y[pt]);
      Y[pt]=MFMA16(a1,b1,Y[pt]);
    }
  }
  // per-thread t rows for P construction
  int tloc = tb*64 + w*16 + quad*4;
  float acst[4];
  #pragma unroll
  for(int r=0;r<4;r++) acst[r] = acs[tloc+r];
  // causal blocks
  for(int sb=0; sb<=tb; sb++){
    __syncthreads();
    {
      int n=tid&63, q4=tid>>6;
      const u16* Bg = XBC + ((size_t)b*CONVDIM + DINNER + n)*LSP + (size_t)c*CHUNK + sb*64;
      #pragma unroll
      for(int i=0;i<2;i++){
        u16x8 v = *(const u16x8*)&Bg[q4*16+i*8];
        #pragma unroll
        for(int j=0;j<8;j++) Bsb[q4*16+i*8+j][n]=v[j];
      }
      const u16* Xg = XBC + ((size_t)b*CONVDIM + h*HEADDIM + n)*LSP + (size_t)c*CHUNK + sb*64;
      #pragma unroll
      for(int i=0;i<2;i++){
        int o = q4*16+i*8;
        u16x8 v = *(const u16x8*)&Xg[o];
        u16x8 wv;
        #pragma unroll
        for(int j=0;j<8;j++) wv[j] = f2bf(bf2f(v[j])*dtv[sb*64+o+j]);
        *(u16x8*)&Xsb[n][o] = wv;
      }
    }
    __syncthreads();
    f32x4 S[4];
    #pragma unroll
    for(int st=0;st<4;st++) S[st]=(f32x4){0.f,0.f,0.f,0.f};
    #pragma unroll
    for(int st=0;st<4;st++){
      u16x8 b0 = *(const u16x8*)&Bsb[st*16+l15][quad*8];
      u16x8 b1 = *(const u16x8*)&Bsb[st*16+l15][32+quad*8];
      S[st]=MFMA16(ca0,b0,S[st]);
      S[st]=MFMA16(ca1,b1,S[st]);
    }
    if (sb < tb){
      #pragma unroll
      for(int st=0;st<4;st++){
        float as = acs[sb*64 + st*16 + l15];
        #pragma unroll
        for(int r=0;r<4;r++)
          P[w][quad*4+r][st*16+l15] = f2bf(S[st][r]*expf(acst[r]-as));
      }
    } else {
      #pragma unroll
      for(int st=0;st<4;st++){
        int s = sb*64 + st*16 + l15;
        float as = acs[s];
        #pragma unroll
        for(int r=0;r<4;r++){
          float e = (s <= tloc+r) ? expf(acst[r]-as) : 0.f;
          P[w][quad*4+r][st*16+l15] = f2bf(S[st][r]*e);
        }
      }
    }
    u16x8 p0 = *(const u16x8*)&P[w][l15][quad*8];
    u16x8 p1 = *(const u16x8*)&P[w][l15][32+quad*8];
    #pragma unroll
    for(int pt=0;pt<4;pt++){
      u16x8 x0 = *(const u16x8*)&Xsb[pt*16+l15][quad*8];
      u16x8 x1 = *(const u16x8*)&Xsb[pt*16+l15][32+quad*8];
      Y[pt]=MFMA16(p0,x0,Y[pt]);
      Y[pt]=MFMA16(p1,x1,Y[pt]);
    }
  }
  // epilogue: + D*xs (Xsb still holds the sb==tb band), write YG [l][d]
  float Dh = Dp[h];
  size_t lbase = (size_t)b*LSP + c*CHUNK + tb*64;
  #pragma unroll
  for(int pt=0;pt<4;pt++){
    #pragma unroll
    for(int r=0;r<4;r++){
      int tl = w*16 + quad*4 + r;
      int p = pt*16 + l15;
      float xdt = bf2f(Xsb[p][tl]);
      float xs = xdt / dtv[tb*64 + tl];
      float y = Y[pt][r] + Dh*xs;
      YG[(lbase + tl)*DINNER + h*HEADDIM + p] = f2bf(y);
    }
  }
}

// ---------------- gate (silu(z)) + RMSNorm, IN-PLACE on YG [l][d]; ZT [l][d] --------
__global__ void gate_kernel(u16* __restrict__ YG, const u16* __restrict__ ZT,
                            const float* __restrict__ rmsw){
  __shared__ float rw[DINNER];
  int tid = threadIdx.x;
  for (int i=tid;i<DINNER;i+=256) rw[i]=rmsw[i];
  __syncthreads();
  int wv = tid>>6, lane = tid&63;
  size_t row = (size_t)blockIdx.x*4 + wv;
  size_t base = row*DINNER + lane*8;
  u16x8 yv = *(const u16x8*)&YG[base];
  u16x8 zv = *(const u16x8*)&ZT[base];
  float g[8]; float sq=0.f;
  #pragma unroll
  for(int j=0;j<8;j++){
    g[j] = bf2f(yv[j]) * siluf(bf2f(zv[j]));
    sq += g[j]*g[j];
  }
  #pragma unroll
  for(int o=32;o>0;o>>=1) sq += __shfl_xor(sq, o, 64);
  float rinv = rsqrtf(sq*(1.f/DINNER) + 1e-5f);
  u16x8 ov;
  #pragma unroll
  for(int j=0;j<8;j++) ov[j] = f2bf(g[j]*rinv*rw[lane*8+j]);
  *(u16x8*)&YG[base] = ov;
}

extern "C" void kernel_launch(void* const* d_in, const int* in_sizes, int n_in,
                              void* d_out, int out_size, void* d_ws, size_t ws_size,
                              hipStream_t stream) {
  const float* x     = (const float*)d_in[0];
  const float* lnw   = (const float*)d_in[1];
  const float* lnb   = (const float*)d_in[2];
  const float* inpw  = (const float*)d_in[3];
  const float* convw = (const float*)d_in[4];
  const float* convb = (const float*)d_in[5];
  const float* alog  = (const float*)d_in[6];
  const float* Dp    = (const float*)d_in[7];
  const float* dtbi  = (const float*)d_in[8];
  const float* rmsw  = (const float*)d_in[9];
  const float* outw  = (const float*)d_in[10];
  float* out = (float*)d_out;

  char* ws = (char*)d_ws;
  size_t off = 0;
  auto alloc = [&](size_t bytes)->void*{ void* p = ws+off; off += (bytes+255)&~(size_t)255; return p; };
  u16*   WPIN   = (u16*)  alloc((size_t)MPAD*DIMC*2);
  u16*   WPOUT  = (u16*)  alloc((size_t)DIMC*DINNER*2);
  char*  RA     = (char*) alloc((size_t)BATCH*NHEADS*NCHUNK*4096*4);
  u16*   XNT    = (u16*)RA;
  float* STATES = (float*)RA;
  u16*   ZT     = (u16*)  alloc((size_t)BATCH*LSP*DINNER*2);
  u16*   XBC    = (u16*)  alloc((size_t)BATCH*CONVDIM*LSP*2);
  u16*   DTb    = (u16*)  alloc((size_t)BATCH*NHEADS*LSP*2);
  u16*   PREVB  = (u16*)  alloc((size_t)BATCH*NHEADS*NCHUNK*4096*2);
  float* DASUM  = (float*)alloc((size_t)BATCH*NHEADS*NCHUNK*4);
  float* ACS    = (float*)alloc((size_t)BATCH*NHEADS*LSP*4);
  float* DTV    = (float*)alloc((size_t)BATCH*NHEADS*LSP*4);
  u16*   YG     = (u16*)  alloc((size_t)BATCH*LSP*DINNER*2);

  convert_w<<<(MPAD*DIMC+255)/256,256,0,stream>>>(inpw, WPIN, MPAD*DIMC, DPROJ*DIMC);
  convert_w<<<(DIMC*DINNER+255)/256,256,0,stream>>>(outw, WPOUT, DIMC*DINNER, DIMC*DINNER);
  ln_kernel<<<dim3(BATCH*LSP/256),256,0,stream>>>(x,lnw,lnb,XNT);
  gemm_zt_mfma<<<dim3(DINNER/128,LSP/128,BATCH),256,0,stream>>>(WPIN, XNT, ZT);
  gemm_xbcdt_mfma<<<dim3(LSP/128,(MPAD-DINNER)/128,BATCH),256,0,stream>>>(WPIN, XNT, XBC, DTb);
  conv_kernel<<<dim3(CONVDIM,BATCH),256,0,stream>>>(XBC, convw, convb);
  ssd_pre_kernel<<<dim3(NCHUNK,NHEADS,BATCH),256,0,stream>>>(DTb, alog, dtbi, ACS, DTV, DASUM);
  ssd_states_mfma<<<dim3(NCHUNK,NHEADS,BATCH),256,0,stream>>>(ACS,DTV,DASUM,XBC,STATES);
  ssd_scan_kernel<<<dim3(16,NHEADS,BATCH),256,0,stream>>>(STATES,DASUM,PREVB);
  ssd_y_mfma<<<dim3(NCHUNK*4,NHEADS,BATCH),256,0,stream>>>(ACS,DTV,XBC,Dp,PREVB,YG);
  gate_kernel<<<dim3(BATCH*LSP/4),256,0,stream>>>(YG,ZT,rmsw);
  gemm_out_mfma<<<dim3(LSP/128,DIMC/128,BATCH),256,0,stream>>>(WPOUT, YG, x, out);
}

// Round 8
// 365.951 us; speedup vs baseline: 4.3087x; 1.0525x over previous
//
#include <hip/hip_runtime.h>
#include <hip/hip_bf16.h>
#include <math.h>

#define DIMC   256
#define LSP    4096
#define BATCH  8
#define DINNER 512
#define NHEADS 8
#define HEADDIM 64
#define DSTATE 64
#define CONVDIM 640
#define DPROJ  1160
#define MPAD   1280
#define CHUNK  256
#define NCHUNK 16

typedef unsigned short u16;
typedef __attribute__((ext_vector_type(8))) unsigned short u16x8;
typedef __attribute__((ext_vector_type(8))) short s16x8;
typedef __attribute__((ext_vector_type(4))) float f32x4;

#define MFMA16(a,b,c) __builtin_amdgcn_mfma_f32_16x16x32_bf16((s16x8)(a),(s16x8)(b),(c),0,0,0)

__device__ __forceinline__ float bf2f(u16 u){ return __uint_as_float(((unsigned int)u)<<16); }
__device__ __forceinline__ u16 f2bf(float f){
  unsigned int x = __float_as_uint(f);
  unsigned int r = (x + 0x7fffu + ((x>>16)&1u)) >> 16;
  return (u16)r;
}
__device__ __forceinline__ float softplusf(float x){ return (x > 20.f) ? x : log1pf(expf(x)); }
__device__ __forceinline__ float siluf(float x){ return x / (1.f + expf(-x)); }

// ---------------- weight fp32 -> bf16 (with trailing-row zero pad) ----------------
__global__ void convert_w(const float* __restrict__ src, u16* __restrict__ dst,
                          int total, int valid){
  int i = blockIdx.x*256 + threadIdx.x;
  if (i >= total) return;
  dst[i] = (i < valid) ? f2bf(src[i]) : (u16)0;
}

// ---------------- out_proj weight * rmsw fold -> bf16 ----------------
__global__ void convert_w_rms(const float* __restrict__ src, const float* __restrict__ rmsw,
                              u16* __restrict__ dst){
  int i = blockIdx.x*256 + threadIdx.x;
  if (i >= DIMC*DINNER) return;
  dst[i] = f2bf(src[i] * rmsw[i & (DINNER-1)]);
}

// ---------------- LayerNorm: x [b][c][l] fp32 -> XNT [b][l][c] bf16 ----------------
__global__ void ln_kernel(const float* __restrict__ X, const float* __restrict__ lnw,
                          const float* __restrict__ lnb, u16* __restrict__ XNT) {
  int pos = blockIdx.x*256 + threadIdx.x;
  int b = pos >> 12, l = pos & (LSP-1);
  const float* xb = X + ((size_t)b*DIMC)*LSP + l;
  float sum=0.f, sq=0.f;
  for (int c=0;c<DIMC;c++){ float v=xb[(size_t)c*LSP]; sum+=v; sq+=v*v; }
  float mu = sum*(1.f/DIMC);
  float var = sq*(1.f/DIMC) - mu*mu;
  float rs = rsqrtf(var + 1e-5f);
  u16* ob = XNT + ((size_t)(b*LSP + l))*DIMC;
  for (int c0=0;c0<DIMC;c0+=8){
    u16x8 v8;
    #pragma unroll
    for(int j=0;j<8;j++){
      float v = xb[(size_t)(c0+j)*LSP];
      v8[j] = f2bf((v-mu)*rs*lnw[c0+j] + lnb[c0+j]);
    }
    *(u16x8*)&ob[c0] = v8;
  }
}

// ---------------- Fused in_proj GEMM: XNT tile LDS-resident, loop over 5 proj tiles.
// proj tiles 0..3 -> ZT [b][l][d] (roles: A=XNT rows l); tiles 4..9 -> XBC/DT planar.
__global__ __launch_bounds__(256,2) void gemm_in_fused(
    const u16* __restrict__ W, const u16* __restrict__ XNT,
    u16* __restrict__ ZT, u16* __restrict__ XBC, u16* __restrict__ DT){
  __shared__ u16 Xs[128][264];
  __shared__ u16 Ws[128][32];
  int tid=threadIdx.x, w=tid>>6, lane=tid&63, l15=lane&15, quad=lane>>4;
  int n0=blockIdx.x*128, mh=blockIdx.y, b=blockIdx.z;
  {
    const u16* src = XNT + ((size_t)(b*LSP + n0))*DIMC;
    #pragma unroll
    for (int i=0;i<16;i++){
      int g = i*256 + tid;
      int row = g>>5, c8 = (g&31)*8;
      *(u16x8*)&Xs[row][c8] = *(const u16x8*)&src[(size_t)row*DIMC + c8];
    }
  }
  for (int pti=0; pti<5; pti++){
    int ptg = mh*5 + pti;
    int m0 = ptg*128;
    f32x4 acc[4][4];
    #pragma unroll
    for(int i=0;i<4;i++)
      #pragma unroll
      for(int j=0;j<4;j++) acc[i][j]=(f32x4){0.f,0.f,0.f,0.f};
    for (int k0=0;k0<DIMC;k0+=32){
      __syncthreads();
      {
        int ch = tid*2;
        int r = ch>>2, o=(ch&3)*8;
        *(u16x8*)&Ws[r][o] = *(const u16x8*)&W[(size_t)(m0+r)*DIMC + k0 + o];
        ch++; r = ch>>2; o=(ch&3)*8;
        *(u16x8*)&Ws[r][o] = *(const u16x8*)&W[(size_t)(m0+r)*DIMC + k0 + o];
      }
      __syncthreads();
      u16x8 af[4], bfr[4];
      if (ptg < 4){
        #pragma unroll
        for(int mt=0;mt<4;mt++) af[mt] = *(const u16x8*)&Xs[(w>>1)*64+mt*16+l15][k0+quad*8];
        #pragma unroll
        for(int nt=0;nt<4;nt++) bfr[nt] = *(const u16x8*)&Ws[(w&1)*64+nt*16+l15][quad*8];
      } else {
        #pragma unroll
        for(int mt=0;mt<4;mt++) af[mt] = *(const u16x8*)&Ws[(w>>1)*64+mt*16+l15][quad*8];
        #pragma unroll
        for(int nt=0;nt<4;nt++) bfr[nt] = *(const u16x8*)&Xs[(w&1)*64+nt*16+l15][k0+quad*8];
      }
      #pragma unroll
      for(int mt=0;mt<4;mt++)
        #pragma unroll
        for(int nt=0;nt<4;nt++)
          acc[mt][nt]=MFMA16(af[mt],bfr[nt],acc[mt][nt]);
    }
    if (ptg < 4){
      #pragma unroll
      for(int mt=0;mt<4;mt++)
        #pragma unroll
        for(int nt=0;nt<4;nt++)
          #pragma unroll
          for(int r=0;r<4;r++){
            int lrow = n0 + (w>>1)*64 + mt*16 + quad*4 + r;
            int dcol = m0 + (w&1)*64 + nt*16 + l15;
            ZT[((size_t)b*LSP + lrow)*DINNER + dcol] = f2bf(acc[mt][nt][r]);
          }
    } else {
      #pragma unroll
      for(int mt=0;mt<4;mt++)
        #pragma unroll
        for(int nt=0;nt<4;nt++)
          #pragma unroll
          for(int r=0;r<4;r++){
            int prow = m0 + (w>>1)*64 + mt*16 + quad*4 + r;
            if (prow>=DPROJ) continue;
            int col = n0 + (w&1)*64 + nt*16 + l15;
            u16 v = f2bf(acc[mt][nt][r]);
            if (prow<DINNER+CONVDIM)  XBC[((size_t)b*CONVDIM+(prow-DINNER))*LSP+col]=v;
            else                      DT[((size_t)b*NHEADS+(prow-DINNER-CONVDIM))*LSP+col]=v;
          }
    }
  }
}

// ---------------- GEMM2 (MFMA): W2' [256x512] x g [b,l,512], *rinv[l] + x -> fp32 ----
__global__ void gemm_out_mfma(const u16* __restrict__ A, const u16* __restrict__ Bm,
                              const float* __restrict__ Res, float* __restrict__ Out){
  __shared__ u16 As[128][32];
  __shared__ u16 Bs[128][32];
  __shared__ float rinv[128];
  int tid=threadIdx.x, w=tid>>6, lane=tid&63, l15=lane&15, quad=lane>>4;
  int b=blockIdx.z, m0=blockIdx.y*128, n0=blockIdx.x*128;
  const u16* Bb = Bm + ((size_t)b*LSP + n0)*DINNER;
  // prologue: per-row rms over the gated g rows
  for (int rr=w; rr<128; rr+=4){
    u16x8 v = *(const u16x8*)&Bb[(size_t)rr*DINNER + lane*8];
    float s=0.f;
    #pragma unroll
    for(int j=0;j<8;j++){ float f=bf2f(v[j]); s+=f*f; }
    #pragma unroll
    for(int o=32;o>0;o>>=1) s += __shfl_xor(s,o,64);
    if (lane==0) rinv[rr] = rsqrtf(s*(1.f/DINNER) + 1e-5f);
  }
  f32x4 acc[4][4];
  #pragma unroll
  for(int i=0;i<4;i++)
    #pragma unroll
    for(int j=0;j<4;j++) acc[i][j] = (f32x4){0.f,0.f,0.f,0.f};
  for (int k0=0;k0<DINNER;k0+=32){
    __syncthreads();
    {
      int ch = tid*2;
      int r = ch>>2, o=(ch&3)*8;
      *(u16x8*)&As[r][o] = *(const u16x8*)&A[(size_t)(m0+r)*DINNER + k0 + o];
      *(u16x8*)&Bs[r][o] = *(const u16x8*)&Bb[(size_t)r*DINNER + k0 + o];
      ch++; r = ch>>2; o=(ch&3)*8;
      *(u16x8*)&As[r][o] = *(const u16x8*)&A[(size_t)(m0+r)*DINNER + k0 + o];
      *(u16x8*)&Bs[r][o] = *(const u16x8*)&Bb[(size_t)r*DINNER + k0 + o];
    }
    __syncthreads();
    u16x8 af[4], bfr[4];
    #pragma unroll
    for(int mt=0;mt<4;mt++) af[mt] = *(const u16x8*)&As[(w>>1)*64+mt*16+l15][quad*8];
    #pragma unroll
    for(int nt=0;nt<4;nt++) bfr[nt] = *(const u16x8*)&Bs[(w&1)*64+nt*16+l15][quad*8];
    #pragma unroll
    for(int mt=0;mt<4;mt++)
      #pragma unroll
      for(int nt=0;nt<4;nt++)
        acc[mt][nt]=MFMA16(af[mt],bfr[nt],acc[mt][nt]);
  }
  #pragma unroll
  for(int mt=0;mt<4;mt++)
    #pragma unroll
    for(int nt=0;nt<4;nt++){
      float rv = rinv[(w&1)*64 + nt*16 + l15];
      #pragma unroll
      for(int r=0;r<4;r++){
        int row = m0 + (w>>1)*64 + mt*16 + quad*4 + r;
        int col = n0 + (w&1)*64 + nt*16 + l15;
        size_t oi = ((size_t)b*DIMC+row)*LSP+col;
        Out[oi] = acc[mt][nt][r]*rv + Res[oi];
      }
    }
}

// ---------------- Depthwise 3x3 conv + bias + SiLU, IN-PLACE on XBC ----------------
__global__ void conv_kernel(u16* __restrict__ XBC, const float* __restrict__ CW,
                            const float* __restrict__ CB){
  int ch = blockIdx.x, b = blockIdx.y, tid = threadIdx.x;
  __shared__ float plane[66*66];
  u16* base = XBC + ((size_t)b*CONVDIM + ch)*LSP;
  for (int idx=tid; idx<66*66; idx+=256){
    int yy = idx/66 - 1, xx = idx%66 - 1;
    float v = 0.f;
    if (yy>=0 && yy<64 && xx>=0 && xx<64) v = bf2f(base[yy*64+xx]);
    plane[idx] = v;
  }
  float wg[9];
  #pragma unroll
  for (int t=0;t<9;t++) wg[t] = CW[ch*9+t];
  float bias = CB[ch];
  __syncthreads();
  for (int r=0;r<16;r++){
    int pix = tid + r*256;
    int y = pix>>6, x = pix&63;
    float s=0.f;
    #pragma unroll
    for(int dy=0;dy<3;dy++)
      #pragma unroll
      for(int dx=0;dx<3;dx++) s += plane[(y+dy)*66 + x+dx]*wg[dy*3+dx];
    base[pix] = f2bf(siluf(s + bias));
  }
}

// ---------------- SSD pre: dt softplus + per-chunk cumsum, done ONCE ----------------
__global__ void ssd_pre_kernel(const u16* __restrict__ DT, const float* __restrict__ A_log,
                               const float* __restrict__ dt_bias, float* __restrict__ ACS,
                               float* __restrict__ DTV, float* __restrict__ DASUM){
  int c=blockIdx.x, h=blockIdx.y, b=blockIdx.z, tid=threadIdx.x;
  __shared__ float acs[CHUNK];
  size_t base = ((size_t)b*NHEADS+h)*LSP + c*CHUNK + tid;
  float raw = bf2f(DT[base]);
  float dtv = softplusf(raw + dt_bias[h]);
  float Ah = -expf(A_log[h]);
  acs[tid] = dtv*Ah;
  __syncthreads();
  for(int o=1;o<256;o<<=1){
    float add=(tid>=o)?acs[tid-o]:0.f;
    __syncthreads(); acs[tid]+=add; __syncthreads();
  }
  ACS[base] = acs[tid];
  DTV[base] = dtv;
  if (tid==CHUNK-1) DASUM[((size_t)b*NHEADS+h)*NCHUNK+c] = acs[tid];
}

// ---------------- SSD states (MFMA): states_T[p][n] = sum_t Xdtw[t][p]*B[t][n] ------
__global__ __launch_bounds__(256,4) void ssd_states_mfma(
    const float* __restrict__ ACS, const float* __restrict__ DTV,
    const float* __restrict__ DASUM, const u16* __restrict__ XBC,
    float* __restrict__ STATES){
  int c=blockIdx.x, h=blockIdx.y, b=blockIdx.z;
  int tid=threadIdx.x, w=tid>>6, lane=tid&63, l15=lane&15, quad=lane>>4;
  __shared__ float wdt[CHUNK];
  __shared__ u16 Xw[64][136];
  __shared__ u16 Bn[64][136];
  {
    size_t base = ((size_t)b*NHEADS+h)*LSP + c*CHUNK + tid;
    float atot = DASUM[((size_t)b*NHEADS+h)*NCHUNK+c];
    wdt[tid] = DTV[base]*expf(atot - ACS[base]);
  }
  __syncthreads();
  f32x4 acc[4];
  #pragma unroll
  for(int i=0;i<4;i++) acc[i] = (f32x4){0.f,0.f,0.f,0.f};
  size_t cb = (size_t)c*CHUNK;
  for(int th=0; th<2; th++){
    __syncthreads();
    {
      int n=tid&63, q4=tid>>6;
      const u16* Xg = XBC + ((size_t)b*CONVDIM + h*HEADDIM + n)*LSP + cb + th*128;
      const u16* Bg = XBC + ((size_t)b*CONVDIM + DINNER + n)*LSP + cb + th*128;
      #pragma unroll
      for(int i=0;i<4;i++){
        int o = q4*32+i*8;
        u16x8 v = *(const u16x8*)&Xg[o];
        u16x8 wv;
        #pragma unroll
        for(int j=0;j<8;j++) wv[j]=f2bf(bf2f(v[j])*wdt[th*128+o+j]);
        *(u16x8*)&Xw[n][o]=wv;
        *(u16x8*)&Bn[n][o] = *(const u16x8*)&Bg[o];
      }
    }
    __syncthreads();
    #pragma unroll
    for(int k8=0;k8<4;k8++){
      u16x8 a = *(const u16x8*)&Xw[w*16+l15][k8*32+quad*8];
      #pragma unroll
      for(int nt=0;nt<4;nt++){
        u16x8 bb = *(const u16x8*)&Bn[nt*16+l15][k8*32+quad*8];
        acc[nt]=MFMA16(a,bb,acc[nt]);
      }
    }
  }
  float* dst = STATES + (((size_t)b*NHEADS+h)*NCHUNK+c)*4096;
  #pragma unroll
  for(int nt=0;nt<4;nt++)
    #pragma unroll
    for(int r=0;r<4;r++)
      dst[(w*16+quad*4+r)*64 + nt*16+l15] = acc[nt][r];
}

// ---------------- inter-chunk scan -> PREVB bf16 [p][n] per (b,h,c) ----------------
__global__ void ssd_scan_kernel(const float* __restrict__ STATES, const float* __restrict__ DASUM,
                                u16* __restrict__ PREVB){
  int g = blockIdx.x, h = blockIdx.y, b = blockIdx.z, tid = threadIdx.x;
  int e = g*256 + tid;
  size_t hb = (size_t)b*NHEADS + h;
  size_t base = hb*NCHUNK*4096 + e;
  float s = 0.f;
  for (int cc=0;cc<NCHUNK;cc++){
    PREVB[base + (size_t)cc*4096] = f2bf(s);
    s = s*expf(DASUM[hb*NCHUNK + cc]) + STATES[base + (size_t)cc*4096];
  }
}

// ---------------- SSD Y (MFMA, flash-style) + silu(z) gate fused ----------------
__global__ __launch_bounds__(256,4) void ssd_y_mfma(
    const float* __restrict__ ACS, const float* __restrict__ DTV,
    const u16* __restrict__ XBC, const float* __restrict__ Dp,
    const u16* __restrict__ PREVB, const u16* __restrict__ ZT,
    u16* __restrict__ YG){
  int bx = blockIdx.x; int c = bx>>2, tb = bx&3;
  int h = blockIdx.y, b = blockIdx.z;
  int tid=threadIdx.x, w=tid>>6, lane=tid&63, l15=lane&15, quad=lane>>4;
  __shared__ float acs[CHUNK];
  __shared__ float dtv[CHUNK];
  __shared__ u16 Ct[64][72];
  __shared__ u16 Bsb[64][72];
  __shared__ u16 Xsb[64][72];
  __shared__ u16 P[4][16][72];
  {
    size_t base = ((size_t)b*NHEADS+h)*LSP + c*CHUNK + tid;
    acs[tid] = ACS[base];
    dtv[tid] = DTV[base];
  }
  // stage C band [64t][64n] (transpose)
  {
    int n = tid&63, q4 = tid>>6;
    const u16* Cg = XBC + ((size_t)b*CONVDIM + DINNER + DSTATE + n)*LSP + (size_t)c*CHUNK + tb*64;
    #pragma unroll
    for(int i=0;i<2;i++){
      u16x8 v = *(const u16x8*)&Cg[q4*16+i*8];
      #pragma unroll
      for(int j=0;j<8;j++) Ct[q4*16+i*8+j][n]=v[j];
    }
  }
  __syncthreads();
  f32x4 Yd[4], Yo[4];
  #pragma unroll
  for(int i=0;i<4;i++){ Yd[i]=(f32x4){0.f,0.f,0.f,0.f}; Yo[i]=(f32x4){0.f,0.f,0.f,0.f}; }
  int trow = w*16 + l15;
  u16x8 ca0 = *(const u16x8*)&Ct[trow][quad*8];
  u16x8 ca1 = *(const u16x8*)&Ct[trow][32+quad*8];
  // Y_off (unscaled): C . prev
  {
    const u16* Pg = PREVB + (((size_t)b*NHEADS+h)*NCHUNK + c)*4096;
    #pragma unroll
    for(int pt=0;pt<4;pt++){
      u16x8 b0 = *(const u16x8*)&Pg[(pt*16+l15)*64 + quad*8];
      u16x8 b1 = *(const u16x8*)&Pg[(pt*16+l15)*64 + 32 + quad*8];
      Yo[pt]=MFMA16(ca0,b0,Yo[pt]);
      Yo[pt]=MFMA16(ca1,b1,Yo[pt]);
    }
  }
  int tloc = tb*64 + w*16 + quad*4;
  float acst[4];
  #pragma unroll
  for(int r=0;r<4;r++) acst[r] = acs[tloc+r];
  // causal blocks; X staged RAW, dtv folded into P
  for(int sb=0; sb<=tb; sb++){
    __syncthreads();
    {
      int n=tid&63, q4=tid>>6;
      const u16* Bg = XBC + ((size_t)b*CONVDIM + DINNER + n)*LSP + (size_t)c*CHUNK + sb*64;
      #pragma unroll
      for(int i=0;i<2;i++){
        u16x8 v = *(const u16x8*)&Bg[q4*16+i*8];
        #pragma unroll
        for(int j=0;j<8;j++) Bsb[q4*16+i*8+j][n]=v[j];
      }
      const u16* Xg = XBC + ((size_t)b*CONVDIM + h*HEADDIM + n)*LSP + (size_t)c*CHUNK + sb*64;
      #pragma unroll
      for(int i=0;i<2;i++){
        int o = q4*16+i*8;
        *(u16x8*)&Xsb[n][o] = *(const u16x8*)&Xg[o];
      }
    }
    __syncthreads();
    f32x4 S[4];
    #pragma unroll
    for(int st=0;st<4;st++) S[st]=(f32x4){0.f,0.f,0.f,0.f};
    #pragma unroll
    for(int st=0;st<4;st++){
      u16x8 b0 = *(const u16x8*)&Bsb[st*16+l15][quad*8];
      u16x8 b1 = *(const u16x8*)&Bsb[st*16+l15][32+quad*8];
      S[st]=MFMA16(ca0,b0,S[st]);
      S[st]=MFMA16(ca1,b1,S[st]);
    }
    if (sb < tb){
      #pragma unroll
      for(int st=0;st<4;st++){
        int s = sb*64 + st*16 + l15;
        float as = acs[s];
        float dv = dtv[s];
        #pragma unroll
        for(int r=0;r<4;r++)
          P[w][quad*4+r][st*16+l15] = f2bf(S[st][r]*expf(acst[r]-as)*dv);
      }
    } else {
      #pragma unroll
      for(int st=0;st<4;st++){
        int s = sb*64 + st*16 + l15;
        float as = acs[s];
        float dv = dtv[s];
        #pragma unroll
        for(int r=0;r<4;r++){
          float e = (s <= tloc+r) ? expf(acst[r]-as) : 0.f;
          P[w][quad*4+r][st*16+l15] = f2bf(S[st][r]*e*dv);
        }
      }
    }
    u16x8 p0 = *(const u16x8*)&P[w][l15][quad*8];
    u16x8 p1 = *(const u16x8*)&P[w][l15][32+quad*8];
    #pragma unroll
    for(int pt=0;pt<4;pt++){
      u16x8 x0 = *(const u16x8*)&Xsb[pt*16+l15][quad*8];
      u16x8 x1 = *(const u16x8*)&Xsb[pt*16+l15][32+quad*8];
      Yd[pt]=MFMA16(p0,x0,Yd[pt]);
      Yd[pt]=MFMA16(p1,x1,Yd[pt]);
    }
  }
  // epilogue: y = Yd + exp(acs[t])*Yo + D*x; g = y*silu(z); write YG [l][d]
  float Dh = Dp[h];
  float eat[4];
  #pragma unroll
  for(int r=0;r<4;r++) eat[r] = expf(acst[r]);
  size_t lbase = (size_t)b*LSP + c*CHUNK + tb*64;
  #pragma unroll
  for(int pt=0;pt<4;pt++){
    #pragma unroll
    for(int r=0;r<4;r++){
      int tl = w*16 + quad*4 + r;
      int p = pt*16 + l15;
      float xs = bf2f(Xsb[p][tl]);
      float y = Yd[pt][r] + eat[r]*Yo[pt][r] + Dh*xs;
      size_t oi = (lbase + tl)*DINNER + h*HEADDIM + p;
      float zv = bf2f(ZT[oi]);
      YG[oi] = f2bf(y * siluf(zv));
    }
  }
}

extern "C" void kernel_launch(void* const* d_in, const int* in_sizes, int n_in,
                              void* d_out, int out_size, void* d_ws, size_t ws_size,
                              hipStream_t stream) {
  const float* x     = (const float*)d_in[0];
  const float* lnw   = (const float*)d_in[1];
  const float* lnb   = (const float*)d_in[2];
  const float* inpw  = (const float*)d_in[3];
  const float* convw = (const float*)d_in[4];
  const float* convb = (const float*)d_in[5];
  const float* alog  = (const float*)d_in[6];
  const float* Dp    = (const float*)d_in[7];
  const float* dtbi  = (const float*)d_in[8];
  const float* rmsw  = (const float*)d_in[9];
  const float* outw  = (const float*)d_in[10];
  float* out = (float*)d_out;

  char* ws = (char*)d_ws;
  size_t off = 0;
  auto alloc = [&](size_t bytes)->void*{ void* p = ws+off; off += (bytes+255)&~(size_t)255; return p; };
  u16*   WPIN   = (u16*)  alloc((size_t)MPAD*DIMC*2);
  u16*   WPOUT  = (u16*)  alloc((size_t)DIMC*DINNER*2);
  char*  RA     = (char*) alloc((size_t)BATCH*NHEADS*NCHUNK*4096*4);
  u16*   XNT    = (u16*)RA;
  float* STATES = (float*)RA;
  u16*   ZT     = (u16*)  alloc((size_t)BATCH*LSP*DINNER*2);
  u16*   XBC    = (u16*)  alloc((size_t)BATCH*CONVDIM*LSP*2);
  u16*   DTb    = (u16*)  alloc((size_t)BATCH*NHEADS*LSP*2);
  u16*   PREVB  = (u16*)  alloc((size_t)BATCH*NHEADS*NCHUNK*4096*2);
  float* DASUM  = (float*)alloc((size_t)BATCH*NHEADS*NCHUNK*4);
  float* ACS    = (float*)alloc((size_t)BATCH*NHEADS*LSP*4);
  float* DTV    = (float*)alloc((size_t)BATCH*NHEADS*LSP*4);
  u16*   YG     = (u16*)  alloc((size_t)BATCH*LSP*DINNER*2);

  convert_w<<<(MPAD*DIMC+255)/256,256,0,stream>>>(inpw, WPIN, MPAD*DIMC, DPROJ*DIMC);
  convert_w_rms<<<(DIMC*DINNER+255)/256,256,0,stream>>>(outw, rmsw, WPOUT);
  ln_kernel<<<dim3(BATCH*LSP/256),256,0,stream>>>(x,lnw,lnb,XNT);
  gemm_in_fused<<<dim3(LSP/128,2,BATCH),256,0,stream>>>(WPIN, XNT, ZT, XBC, DTb);
  conv_kernel<<<dim3(CONVDIM,BATCH),256,0,stream>>>(XBC, convw, convb);
  ssd_pre_kernel<<<dim3(NCHUNK,NHEADS,BATCH),256,0,stream>>>(DTb, alog, dtbi, ACS, DTV, DASUM);
  ssd_states_mfma<<<dim3(NCHUNK,NHEADS,BATCH),256,0,stream>>>(ACS,DTV,DASUM,XBC,STATES);
  ssd_scan_kernel<<<dim3(16,NHEADS,BATCH),256,0,stream>>>(STATES,DASUM,PREVB);
  ssd_y_mfma<<<dim3(NCHUNK*4,NHEADS,BATCH),256,0,stream>>>(ACS,DTV,XBC,Dp,PREVB,ZT,YG);
  gemm_out_mfma<<<dim3(LSP/128,DIMC/128,BATCH),256,0,stream>>>(WPOUT, YG, x, out);
}